// Round 2
// baseline (2720.306 us; speedup 1.0000x reference)
//
#include <hip/hip_runtime.h>
#include <math.h>

// Problem constants (B=1)
#define NH    12      // heads
#define NRES  768     // sequence length
#define C1V   384
#define C2V   128
#define NPROJ 1152    // 192+192+192+144+144+288
#define QKD   28      // 16 scalar + 12 point dims
#define FDIM  2112    // 192 + 3*96 + 96 + 1536
#define VVD   480     // 192 (v) + 288 (vp global)

__device__ __forceinline__ float softplusf_(float x) {
    return (x > 20.f) ? x : log1pf(__expf(x));
}

// ---------------------------------------------------------------------------
// K1: proj = act @ [wq|wk|wv|wqp|wkp|wvp] + [0|0|0|bqp|bkp|bvp]
//     M=768, N=1152, K=384. 64x64 tiles, 4x4 micro, 256 threads.
// ---------------------------------------------------------------------------
__global__ __launch_bounds__(256) void k1_proj(
    const float* __restrict__ act,
    const float* __restrict__ wq, const float* __restrict__ wk,
    const float* __restrict__ wv, const float* __restrict__ wqp,
    const float* __restrict__ wkp, const float* __restrict__ wvp,
    const float* __restrict__ bqp, const float* __restrict__ bkp,
    const float* __restrict__ bvp, float* __restrict__ proj)
{
    __shared__ float As[64 * 33];
    __shared__ float Bs[32 * 65];
    const int n0 = blockIdx.x * 64, m0 = blockIdx.y * 64;
    const int tid = threadIdx.x;
    const int tx = tid & 15, ty = tid >> 4;
    float c[4][4] = {};

    for (int kt = 0; kt < C1V; kt += 32) {
        for (int idx = tid; idx < 64 * 32; idx += 256) {
            int r = idx >> 5, j = idx & 31;
            As[r * 33 + j] = act[(m0 + r) * C1V + kt + j];
        }
        for (int idx = tid; idx < 32 * 64; idx += 256) {
            int r = idx >> 6, col = idx & 63;
            int jj = n0 + col, k = kt + r;
            float w;
            if      (jj < 192) w = wq [k * 192 + jj];
            else if (jj < 384) w = wk [k * 192 + jj - 192];
            else if (jj < 576) w = wv [k * 192 + jj - 384];
            else if (jj < 720) w = wqp[k * 144 + jj - 576];
            else if (jj < 864) w = wkp[k * 144 + jj - 720];
            else               w = wvp[k * 288 + jj - 864];
            Bs[r * 65 + col] = w;
        }
        __syncthreads();
        #pragma unroll
        for (int kk = 0; kk < 32; ++kk) {
            float a[4], b[4];
            #pragma unroll
            for (int i = 0; i < 4; ++i) a[i] = As[(ty * 4 + i) * 33 + kk];
            #pragma unroll
            for (int j = 0; j < 4; ++j) b[j] = Bs[kk * 65 + tx * 4 + j];
            #pragma unroll
            for (int i = 0; i < 4; ++i)
                #pragma unroll
                for (int j = 0; j < 4; ++j) c[i][j] += a[i] * b[j];
        }
        __syncthreads();
    }
    float biasv[4];
    #pragma unroll
    for (int j = 0; j < 4; ++j) {
        int col = n0 + tx * 4 + j;
        biasv[j] = (col >= 864) ? bvp[col - 864]
                 : (col >= 720) ? bkp[col - 720]
                 : (col >= 576) ? bqp[col - 576] : 0.f;
    }
    #pragma unroll
    for (int i = 0; i < 4; ++i) {
        float4 v;
        v.x = c[i][0] + biasv[0]; v.y = c[i][1] + biasv[1];
        v.z = c[i][2] + biasv[2]; v.w = c[i][3] + biasv[3];
        *(float4*)&proj[(m0 + ty * 4 + i) * NPROJ + n0 + tx * 4] = v;
    }
}

// ---------------------------------------------------------------------------
// K2: per-residue prep. Qv[n][h][28] (q*0.25 | pw*qp_glob), Kv[n][h][28],
//     ak[n][h] = -0.5*pw*sum|kp|^2, vv[n][480] = [v(192) | vp_global(288)].
// ---------------------------------------------------------------------------
__global__ __launch_bounds__(64) void k2_prep(
    const float* __restrict__ proj, const float* __restrict__ rot,
    const float* __restrict__ trans, const float* __restrict__ tw,
    float* __restrict__ Qv, float* __restrict__ Kv,
    float* __restrict__ akArr, float* __restrict__ vv)
{
    const int n = blockIdx.x, tid = threadIdx.x;
    __shared__ float kp2[48];
    const float* pr = proj + n * NPROJ;
    float R[9], T[3];
    #pragma unroll
    for (int i = 0; i < 9; ++i) R[i] = rot[n * 9 + i];
    #pragma unroll
    for (int i = 0; i < 3; ++i) T[i] = trans[n * 3 + i];

    for (int idx = tid; idx < 192; idx += 64) {
        int h = idx >> 4, cc = idx & 15;
        Qv[(n * NH + h) * QKD + cc] = pr[idx] * 0.25f;          // sqrt(1/16)
        Kv[(n * NH + h) * QKD + cc] = pr[192 + idx];
        vv[n * VVD + idx] = pr[384 + idx];                      // v copy
        vv[n * VVD + 64 + idx] = pr[448 + idx];                 // (covers 192 floats total via stride)
    }
    // NOTE: the loop above writes vv[n][0..191] twice-overlapping; fix: do it explicitly
    __syncthreads();
    for (int idx = tid; idx < 192; idx += 64)
        vv[n * VVD + idx] = pr[384 + idx];

    if (tid < 48) {
        int h = tid >> 2, p = tid & 3;
        float pwh = 0.23570226039551584f * softplusf_(tw[h]);   // sqrt(2/36)*softplus
        // qp
        float lx = pr[576 + h * 12 + p];
        float ly = pr[576 + h * 12 + 4 + p];
        float lz = pr[576 + h * 12 + 8 + p];
        float gx = R[0] * lx + R[1] * ly + R[2] * lz + T[0];
        float gy = R[3] * lx + R[4] * ly + R[5] * lz + T[1];
        float gz = R[6] * lx + R[7] * ly + R[8] * lz + T[2];
        float* qd = &Qv[(n * NH + h) * QKD + 16];
        qd[p] = pwh * gx; qd[4 + p] = pwh * gy; qd[8 + p] = pwh * gz;
        // kp
        lx = pr[720 + h * 12 + p];
        ly = pr[720 + h * 12 + 4 + p];
        lz = pr[720 + h * 12 + 8 + p];
        gx = R[0] * lx + R[1] * ly + R[2] * lz + T[0];
        gy = R[3] * lx + R[4] * ly + R[5] * lz + T[1];
        gz = R[6] * lx + R[7] * ly + R[8] * lz + T[2];
        float* kd = &Kv[(n * NH + h) * QKD + 16];
        kd[p] = gx; kd[4 + p] = gy; kd[8 + p] = gz;
        kp2[tid] = gx * gx + gy * gy + gz * gz;
    }
    __syncthreads();
    if (tid < NH) {
        float pwh = 0.23570226039551584f * softplusf_(tw[tid]);
        akArr[n * NH + tid] = -0.5f * pwh *
            (kp2[tid * 4] + kp2[tid * 4 + 1] + kp2[tid * 4 + 2] + kp2[tid * 4 + 3]);
    }
    for (int idx = tid; idx < 96; idx += 64) {
        int h = idx >> 3, p = idx & 7;
        float lx = pr[864 + h * 24 + p];
        float ly = pr[864 + h * 24 + 8 + p];
        float lz = pr[864 + h * 24 + 16 + p];
        float gx = R[0] * lx + R[1] * ly + R[2] * lz + T[0];
        float gy = R[3] * lx + R[4] * ly + R[5] * lz + T[1];
        float gz = R[6] * lx + R[7] * ly + R[8] * lz + T[2];
        float* dst = &vv[n * VVD + 192 + h * 24 + p * 3];
        dst[0] = gx; dst[1] = gy; dst[2] = gz;
    }
}

// ---------------------------------------------------------------------------
// K2b: qkBuf[q][h][k] = Qv[q,h,:].Kv[k,h,:] + ak[k,h]   (28-deep dot)
// ---------------------------------------------------------------------------
__global__ __launch_bounds__(256) void k2b_qk(
    const float* __restrict__ Qv, const float* __restrict__ Kv,
    const float* __restrict__ akArr, float* __restrict__ qkBuf)
{
    const int h = blockIdx.z;
    const int k0 = blockIdx.x * 64, q0 = blockIdx.y * 64;
    __shared__ float As[64 * 29];
    __shared__ float Bs[64 * 29];
    const int tid = threadIdx.x, tx = tid & 15, ty = tid >> 4;

    for (int idx = tid; idx < 64 * 28; idx += 256) {
        int r = idx / 28, j = idx - r * 28;
        As[r * 29 + j] = Qv[((q0 + r) * NH + h) * QKD + j];
        Bs[r * 29 + j] = Kv[((k0 + r) * NH + h) * QKD + j];
    }
    __syncthreads();
    float c[4][4] = {};
    #pragma unroll
    for (int kk = 0; kk < 28; ++kk) {
        float a[4], b[4];
        #pragma unroll
        for (int i = 0; i < 4; ++i) a[i] = As[(ty * 4 + i) * 29 + kk];
        #pragma unroll
        for (int j = 0; j < 4; ++j) b[j] = Bs[(tx * 4 + j) * 29 + kk];
        #pragma unroll
        for (int i = 0; i < 4; ++i)
            #pragma unroll
            for (int j = 0; j < 4; ++j) c[i][j] += a[i] * b[j];
    }
    float akv[4];
    #pragma unroll
    for (int j = 0; j < 4; ++j) akv[j] = akArr[(k0 + tx * 4 + j) * NH + h];
    #pragma unroll
    for (int i = 0; i < 4; ++i) {
        float4 v;
        v.x = c[i][0] + akv[0]; v.y = c[i][1] + akv[1];
        v.z = c[i][2] + akv[2]; v.w = c[i][3] + akv[3];
        *(float4*)&qkBuf[((q0 + ty * 4 + i) * NH + h) * NRES + k0 + tx * 4] = v;
    }
}

// ---------------------------------------------------------------------------
// KA: qkBuf[q][h][k] = (qkBuf + act2d[q,k,:].w2d[:,h] + mask) * sqrt(1/3)
//     Streams act2d once, coalesced via LDS tile (64 rows x 128 c, pad 132).
//     grid (12 k-tiles, 768 q).
// ---------------------------------------------------------------------------
__global__ __launch_bounds__(256) void kA_bias(
    const float* __restrict__ act2d, const float* __restrict__ smask,
    const float* __restrict__ w2d, float* __restrict__ qkBuf)
{
    const int q = blockIdx.y, k0 = blockIdx.x * 64, tid = threadIdx.x;
    __shared__ float tile[64 * 132];
    __shared__ float w2dS[NH * 128];

    for (int idx = tid; idx < C2V * NH; idx += 256)
        w2dS[(idx % NH) * 128 + (idx / NH)] = w2d[idx];
    const float* src = act2d + ((size_t)q * NRES + k0) * C2V;
    #pragma unroll
    for (int i = 0; i < 8; ++i) {
        int f = tid + i * 256;                // float4 index 0..2047
        float4 v = ((const float4*)src)[f];
        int r = f >> 5, cq = f & 31;
        *(float4*)&tile[r * 132 + cq * 4] = v;
    }
    __syncthreads();

    const float smq = smask[q];
    const float scale = 0.5773502691896258f;  // sqrt(1/3)
    #pragma unroll
    for (int j = 0; j < 3; ++j) {
        int o = tid + j * 256;
        int h = o >> 6, r = o & 63;
        const float* trow = &tile[r * 132];
        const float* wrow = &w2dS[h * 128];
        float4 acc = {0, 0, 0, 0};
        #pragma unroll
        for (int cb = 0; cb < 128; cb += 4) {
            float4 t = *(const float4*)&trow[cb];
            float4 w = *(const float4*)&wrow[cb];
            acc.x += t.x * w.x; acc.y += t.y * w.y;
            acc.z += t.z * w.z; acc.w += t.w * w.w;
        }
        float d = acc.x + acc.y + acc.z + acc.w;
        int k = k0 + r;
        float msk = -1e5f * (1.f - smq * smask[k]);
        size_t qi = ((size_t)(q * NH + h)) * NRES + k;
        qkBuf[qi] = (qkBuf[qi] + d + msk) * scale;
    }
}

// ---------------------------------------------------------------------------
// KC: per-q softmax + attention-weighted sums, streaming act2d in k-tiles.
//   LDS: attnS 12x768 (36 KB) + tile 64x128 (32 KB).
//   Outputs F[q][2112] = [res(192)|rpl_x(96)|rpl_y|rpl_z|norms|r2d(1536)]
// ---------------------------------------------------------------------------
__global__ __launch_bounds__(256, 2) void kC_attn(
    const float* __restrict__ act2d, const float* __restrict__ qkBuf,
    const float* __restrict__ vv, const float* __restrict__ rot,
    const float* __restrict__ trans, float* __restrict__ F)
{
    const int q = blockIdx.x, tid = threadIdx.x;
    __shared__ float attnS[NH * NRES];   // 36 KB
    __shared__ float tile[64 * 128];     // 32 KB
    __shared__ float red[NH * 4];
    __shared__ float mh[NH], lhS[NH];
    __shared__ float rpgS[288];
    __shared__ float rotS[9], transS[3];

    if (tid < 9) rotS[tid] = rot[q * 9 + tid];
    if (tid < 3) transS[tid] = trans[q * 3 + tid];

    // ---- load logits (already masked+scaled by kA) ----
    float lg[3][NH];
    #pragma unroll
    for (int h = 0; h < NH; ++h)
        #pragma unroll
        for (int i = 0; i < 3; ++i)
            lg[i][h] = qkBuf[((size_t)(q * NH + h)) * NRES + tid + 256 * i];

    // ---- softmax over k ----
    const int wv_ = tid >> 6, lane = tid & 63;
    #pragma unroll
    for (int h = 0; h < NH; ++h) {
        float v = fmaxf(fmaxf(lg[0][h], lg[1][h]), lg[2][h]);
        for (int off = 32; off > 0; off >>= 1) v = fmaxf(v, __shfl_down(v, off, 64));
        if (lane == 0) red[h * 4 + wv_] = v;
    }
    __syncthreads();
    if (tid < NH)
        mh[tid] = fmaxf(fmaxf(red[tid * 4], red[tid * 4 + 1]),
                        fmaxf(red[tid * 4 + 2], red[tid * 4 + 3]));
    __syncthreads();
    float lsum[NH];
    #pragma unroll
    for (int h = 0; h < NH; ++h) lsum[h] = 0.f;
    #pragma unroll
    for (int i = 0; i < 3; ++i)
        #pragma unroll
        for (int h = 0; h < NH; ++h) {
            float e = __expf(lg[i][h] - mh[h]);
            attnS[h * NRES + tid + 256 * i] = e;
            lsum[h] += e;
        }
    #pragma unroll
    for (int h = 0; h < NH; ++h) {
        float v = lsum[h];
        for (int off = 32; off > 0; off >>= 1) v += __shfl_down(v, off, 64);
        if (lane == 0) red[h * 4 + wv_] = v;
    }
    __syncthreads();
    if (tid < NH)
        lhS[tid] = 1.f / (red[tid * 4] + red[tid * 4 + 1] + red[tid * 4 + 2] + red[tid * 4 + 3]);
    __syncthreads();
    // normalize attn in LDS
    for (int idx = tid; idx < NH * NRES; idx += 256)
        attnS[idx] *= lhS[idx / NRES];

    // ---- phase B: stream act2d k-tiles ----
    const int h0 = tid >> 5, c0 = (tid & 31) << 2;
    const int h1 = 8 + (tid >> 5);                 // valid for tid<128
    const int s0 = tid;
    const int hs0 = (tid < 192) ? (tid >> 4) : ((tid - 192) / 24);
    const int s1 = 256 + tid;                      // valid tid<224
    const int hs1 = (tid + 64) / 24;
    const float* at0  = attnS + h0 * NRES;
    const float* at1  = attnS + ((h1 < NH) ? h1 : NH - 1) * NRES;
    const float* atS0 = attnS + hs0 * NRES;
    const float* atS1 = attnS + ((hs1 < NH) ? hs1 : NH - 1) * NRES;
    float4 acc0 = {0, 0, 0, 0}, acc1 = {0, 0, 0, 0};
    float accS0 = 0.f, accS1 = 0.f;
    const bool doB = (tid < 128), doS1 = (tid < 224);

    for (int t = 0; t < 12; ++t) {
        const int k0 = t * 64;
        __syncthreads();
        const float* src = act2d + ((size_t)q * NRES + k0) * C2V;
        #pragma unroll
        for (int i = 0; i < 8; ++i) {
            int f = tid + i * 256;
            ((float4*)tile)[f] = ((const float4*)src)[f];
        }
        __syncthreads();
        const float* vk = vv + (size_t)k0 * VVD;
        #pragma unroll
        for (int k4 = 0; k4 < 16; ++k4) {
            float4 p0v = *(const float4*)(at0  + k0 + k4 * 4);
            float4 p1v = *(const float4*)(at1  + k0 + k4 * 4);
            float4 w0v = *(const float4*)(atS0 + k0 + k4 * 4);
            float4 w1v = *(const float4*)(atS1 + k0 + k4 * 4);
            #pragma unroll
            for (int u = 0; u < 4; ++u) {
                int kt = k4 * 4 + u;
                float4 a = *(const float4*)&tile[kt * 128 + c0];
                float p0 = ((const float*)&p0v)[u];
                acc0.x += p0 * a.x; acc0.y += p0 * a.y;
                acc0.z += p0 * a.z; acc0.w += p0 * a.w;
                if (doB) {
                    float p1 = ((const float*)&p1v)[u];
                    acc1.x += p1 * a.x; acc1.y += p1 * a.y;
                    acc1.z += p1 * a.z; acc1.w += p1 * a.w;
                }
                float w0 = ((const float*)&w0v)[u];
                accS0 += w0 * vk[(size_t)kt * VVD + s0];
                if (doS1) {
                    float w1 = ((const float*)&w1v)[u];
                    accS1 += w1 * vk[(size_t)kt * VVD + s1];
                }
            }
        }
    }

    float* Fq = F + q * FDIM;
    *(float4*)(Fq + 576 + tid * 4) = acc0;
    if (doB) *(float4*)(Fq + 576 + (256 + tid) * 4) = acc1;
    if (tid < 192) Fq[tid] = accS0; else rpgS[tid - 192] = accS0;
    if (doS1) rpgS[64 + tid] = accS1;
    __syncthreads();
    if (tid < 96) {
        float gx = rpgS[tid * 3]     - transS[0];
        float gy = rpgS[tid * 3 + 1] - transS[1];
        float gz = rpgS[tid * 3 + 2] - transS[2];
        // invert_apply: rpl_i = sum_j R[j][i] * g_j
        float x = rotS[0] * gx + rotS[3] * gy + rotS[6] * gz;
        float y = rotS[1] * gx + rotS[4] * gy + rotS[7] * gz;
        float z = rotS[2] * gx + rotS[5] * gy + rotS[8] * gz;
        float* Fo = F + q * FDIM;
        Fo[192 + tid] = x;
        Fo[288 + tid] = y;
        Fo[384 + tid] = z;
        Fo[480 + tid] = sqrtf(x * x + y * y + z * z);
    }
}

// ---------------------------------------------------------------------------
// K5: out = F @ wfin + bfin.  M=768, N=384, K=2112. 64x32 tiles, 144 blocks,
//     2x4 micro, no atomics.
// ---------------------------------------------------------------------------
__global__ __launch_bounds__(256) void k5_final(
    const float* __restrict__ F, const float* __restrict__ wfin,
    const float* __restrict__ bfin, float* __restrict__ out)
{
    const int n0 = blockIdx.x * 32, m0 = blockIdx.y * 64;
    __shared__ float As[64 * 33];
    __shared__ float Bs[32 * 36];
    const int tid = threadIdx.x, tx = tid & 7, ty = tid >> 3;
    float c0_[4] = {}, c1_[4] = {};

    for (int kt = 0; kt < FDIM; kt += 32) {
        for (int idx = tid; idx < 64 * 32; idx += 256) {
            int r = idx >> 5, j = idx & 31;
            As[r * 33 + j] = F[(m0 + r) * FDIM + kt + j];
        }
        for (int idx = tid; idx < 32 * 32; idx += 256) {
            int r = idx >> 5, col = idx & 31;
            Bs[r * 36 + col] = wfin[(kt + r) * 384 + n0 + col];
        }
        __syncthreads();
        #pragma unroll
        for (int kk = 0; kk < 32; ++kk) {
            float a0 = As[(ty * 2) * 33 + kk];
            float a1 = As[(ty * 2 + 1) * 33 + kk];
            float4 b = *(const float4*)&Bs[kk * 36 + tx * 4];
            c0_[0] += a0 * b.x; c0_[1] += a0 * b.y; c0_[2] += a0 * b.z; c0_[3] += a0 * b.w;
            c1_[0] += a1 * b.x; c1_[1] += a1 * b.y; c1_[2] += a1 * b.z; c1_[3] += a1 * b.w;
        }
        __syncthreads();
    }
    float4 bias = *(const float4*)&bfin[n0 + tx * 4];
    float4 v0 = {c0_[0] + bias.x, c0_[1] + bias.y, c0_[2] + bias.z, c0_[3] + bias.w};
    float4 v1 = {c1_[0] + bias.x, c1_[1] + bias.y, c1_[2] + bias.z, c1_[3] + bias.w};
    *(float4*)&out[(m0 + ty * 2) * 384 + n0 + tx * 4] = v0;
    *(float4*)&out[(m0 + ty * 2 + 1) * 384 + n0 + tx * 4] = v1;
}

// ---------------------------------------------------------------------------
extern "C" void kernel_launch(void* const* d_in, const int* in_sizes, int n_in,
                              void* d_out, int out_size, void* d_ws, size_t ws_size,
                              hipStream_t stream) {
    const float* act   = (const float*)d_in[0];
    const float* act2d = (const float*)d_in[1];
    const float* smask = (const float*)d_in[2];
    const float* rot   = (const float*)d_in[3];
    const float* trans = (const float*)d_in[4];
    const float* wq    = (const float*)d_in[5];
    const float* wk    = (const float*)d_in[6];
    const float* wvv   = (const float*)d_in[7];
    const float* wqp   = (const float*)d_in[8];
    const float* bqp   = (const float*)d_in[9];
    const float* wkp   = (const float*)d_in[10];
    const float* bkp   = (const float*)d_in[11];
    const float* wvp   = (const float*)d_in[12];
    const float* bvp   = (const float*)d_in[13];
    const float* w2d   = (const float*)d_in[14];
    // d_in[15] = b2d: constant over k, cancels in softmax over k -> unused
    const float* wfin  = (const float*)d_in[16];
    const float* bfin  = (const float*)d_in[17];
    const float* tw    = (const float*)d_in[18];

    // workspace layout (floats); total 10,478,592 floats = 41.9 MB
    float* W     = (float*)d_ws;
    float* proj  = W;                      // 768*1152
    float* Qv    = proj  + 768 * NPROJ;    // 768*12*28
    float* Kv    = Qv    + 768 * NH * QKD;
    float* akArr = Kv    + 768 * NH * QKD; // 768*12
    float* vvA   = akArr + 768 * NH;       // 768*480
    float* qkBuf = vvA   + 768 * VVD;      // 768*12*768
    float* F     = qkBuf + 768 * NH * NRES;// 768*2112

    k1_proj<<<dim3(18, 12), 256, 0, stream>>>(act, wq, wk, wvv, wqp, wkp, wvp,
                                              bqp, bkp, bvp, proj);
    k2_prep<<<dim3(NRES), 64, 0, stream>>>(proj, rot, trans, tw, Qv, Kv, akArr, vvA);
    k2b_qk<<<dim3(12, 12, NH), 256, 0, stream>>>(Qv, Kv, akArr, qkBuf);
    kA_bias<<<dim3(12, NRES), 256, 0, stream>>>(act2d, smask, w2d, qkBuf);
    kC_attn<<<dim3(NRES), 256, 0, stream>>>(act2d, qkBuf, vvA, rot, trans, F);
    k5_final<<<dim3(12, 12), 256, 0, stream>>>(F, wfin, bfin, (float*)d_out);
}

// Round 3
// 902.899 us; speedup vs baseline: 3.0129x; 3.0129x over previous
//
#include <hip/hip_runtime.h>
#include <math.h>

// Problem constants (B=1)
#define NH    12      // heads
#define NRES  768     // sequence length
#define C1V   384
#define C2V   128
#define NPROJ 1152    // 192+192+192+144+144+288
#define QKD   28      // 16 scalar + 12 point dims
#define FDIM  2112    // 192 + 3*96 + 96 + 1536
#define VVD   480     // 192 (v) + 288 (vp global)
#define APAD  772     // attn row pad: (h*772+k)%32 = (4h+k)%32 -> no 12-way alias

__device__ __forceinline__ float softplusf_(float x) {
    return (x > 20.f) ? x : log1pf(__expf(x));
}

// ---------------------------------------------------------------------------
// K1: proj = act @ [wq|wk|wv|wqp|wkp|wvp] + [0|0|0|bqp|bkp|bvp]
// ---------------------------------------------------------------------------
__global__ __launch_bounds__(256) void k1_proj(
    const float* __restrict__ act,
    const float* __restrict__ wq, const float* __restrict__ wk,
    const float* __restrict__ wv, const float* __restrict__ wqp,
    const float* __restrict__ wkp, const float* __restrict__ wvp,
    const float* __restrict__ bqp, const float* __restrict__ bkp,
    const float* __restrict__ bvp, float* __restrict__ proj)
{
    __shared__ float As[64 * 33];
    __shared__ float Bs[32 * 65];
    const int n0 = blockIdx.x * 64, m0 = blockIdx.y * 64;
    const int tid = threadIdx.x;
    const int tx = tid & 15, ty = tid >> 4;
    float c[4][4] = {};

    for (int kt = 0; kt < C1V; kt += 32) {
        for (int idx = tid; idx < 64 * 32; idx += 256) {
            int r = idx >> 5, j = idx & 31;
            As[r * 33 + j] = act[(m0 + r) * C1V + kt + j];
        }
        for (int idx = tid; idx < 32 * 64; idx += 256) {
            int r = idx >> 6, col = idx & 63;
            int jj = n0 + col, k = kt + r;
            float w;
            if      (jj < 192) w = wq [k * 192 + jj];
            else if (jj < 384) w = wk [k * 192 + jj - 192];
            else if (jj < 576) w = wv [k * 192 + jj - 384];
            else if (jj < 720) w = wqp[k * 144 + jj - 576];
            else if (jj < 864) w = wkp[k * 144 + jj - 720];
            else               w = wvp[k * 288 + jj - 864];
            Bs[r * 65 + col] = w;
        }
        __syncthreads();
        #pragma unroll
        for (int kk = 0; kk < 32; ++kk) {
            float a[4], b[4];
            #pragma unroll
            for (int i = 0; i < 4; ++i) a[i] = As[(ty * 4 + i) * 33 + kk];
            #pragma unroll
            for (int j = 0; j < 4; ++j) b[j] = Bs[kk * 65 + tx * 4 + j];
            #pragma unroll
            for (int i = 0; i < 4; ++i)
                #pragma unroll
                for (int j = 0; j < 4; ++j) c[i][j] += a[i] * b[j];
        }
        __syncthreads();
    }
    float biasv[4];
    #pragma unroll
    for (int j = 0; j < 4; ++j) {
        int col = n0 + tx * 4 + j;
        biasv[j] = (col >= 864) ? bvp[col - 864]
                 : (col >= 720) ? bkp[col - 720]
                 : (col >= 576) ? bqp[col - 576] : 0.f;
    }
    #pragma unroll
    for (int i = 0; i < 4; ++i) {
        float4 v;
        v.x = c[i][0] + biasv[0]; v.y = c[i][1] + biasv[1];
        v.z = c[i][2] + biasv[2]; v.w = c[i][3] + biasv[3];
        *(float4*)&proj[(m0 + ty * 4 + i) * NPROJ + n0 + tx * 4] = v;
    }
}

// ---------------------------------------------------------------------------
// K2: per-residue prep. Qv[n][h][28] (q*0.25 | pw*qp_glob), Kv[n][h][28],
//     ak[n][h] = -0.5*pw*sum|kp|^2, vv[n][480] = [v(192) | vp_global(288)].
// ---------------------------------------------------------------------------
__global__ __launch_bounds__(64) void k2_prep(
    const float* __restrict__ proj, const float* __restrict__ rot,
    const float* __restrict__ trans, const float* __restrict__ tw,
    float* __restrict__ Qv, float* __restrict__ Kv,
    float* __restrict__ akArr, float* __restrict__ vv)
{
    const int n = blockIdx.x, tid = threadIdx.x;
    __shared__ float kp2[48];
    const float* pr = proj + n * NPROJ;
    float R[9], T[3];
    #pragma unroll
    for (int i = 0; i < 9; ++i) R[i] = rot[n * 9 + i];
    #pragma unroll
    for (int i = 0; i < 3; ++i) T[i] = trans[n * 3 + i];

    for (int idx = tid; idx < 192; idx += 64) {
        int h = idx >> 4, cc = idx & 15;
        Qv[(n * NH + h) * QKD + cc] = pr[idx] * 0.25f;          // sqrt(1/16)
        Kv[(n * NH + h) * QKD + cc] = pr[192 + idx];
        vv[n * VVD + idx] = pr[384 + idx];                      // v
    }
    if (tid < 48) {
        int h = tid >> 2, p = tid & 3;
        float pwh = 0.23570226039551584f * softplusf_(tw[h]);   // sqrt(2/36)*softplus
        float lx = pr[576 + h * 12 + p];
        float ly = pr[576 + h * 12 + 4 + p];
        float lz = pr[576 + h * 12 + 8 + p];
        float gx = R[0] * lx + R[1] * ly + R[2] * lz + T[0];
        float gy = R[3] * lx + R[4] * ly + R[5] * lz + T[1];
        float gz = R[6] * lx + R[7] * ly + R[8] * lz + T[2];
        float* qd = &Qv[(n * NH + h) * QKD + 16];
        qd[p] = pwh * gx; qd[4 + p] = pwh * gy; qd[8 + p] = pwh * gz;
        lx = pr[720 + h * 12 + p];
        ly = pr[720 + h * 12 + 4 + p];
        lz = pr[720 + h * 12 + 8 + p];
        gx = R[0] * lx + R[1] * ly + R[2] * lz + T[0];
        gy = R[3] * lx + R[4] * ly + R[5] * lz + T[1];
        gz = R[6] * lx + R[7] * ly + R[8] * lz + T[2];
        float* kd = &Kv[(n * NH + h) * QKD + 16];
        kd[p] = gx; kd[4 + p] = gy; kd[8 + p] = gz;
        kp2[tid] = gx * gx + gy * gy + gz * gz;
    }
    __syncthreads();
    if (tid < NH) {
        float pwh = 0.23570226039551584f * softplusf_(tw[tid]);
        akArr[n * NH + tid] = -0.5f * pwh *
            (kp2[tid * 4] + kp2[tid * 4 + 1] + kp2[tid * 4 + 2] + kp2[tid * 4 + 3]);
    }
    for (int idx = tid; idx < 96; idx += 64) {
        int h = idx >> 3, p = idx & 7;
        float lx = pr[864 + h * 24 + p];
        float ly = pr[864 + h * 24 + 8 + p];
        float lz = pr[864 + h * 24 + 16 + p];
        float gx = R[0] * lx + R[1] * ly + R[2] * lz + T[0];
        float gy = R[3] * lx + R[4] * ly + R[5] * lz + T[1];
        float gz = R[6] * lx + R[7] * ly + R[8] * lz + T[2];
        float* dst = &vv[n * VVD + 192 + h * 24 + p * 3];
        dst[0] = gx; dst[1] = gy; dst[2] = gz;
    }
}

// ---------------------------------------------------------------------------
// K2b: qkBuf[q][h][k] = Qv[q,h,:].Kv[k,h,:] + ak[k,h]
// ---------------------------------------------------------------------------
__global__ __launch_bounds__(256) void k2b_qk(
    const float* __restrict__ Qv, const float* __restrict__ Kv,
    const float* __restrict__ akArr, float* __restrict__ qkBuf)
{
    const int h = blockIdx.z;
    const int k0 = blockIdx.x * 64, q0 = blockIdx.y * 64;
    __shared__ float As[64 * 29];
    __shared__ float Bs[64 * 29];
    const int tid = threadIdx.x, tx = tid & 15, ty = tid >> 4;

    for (int idx = tid; idx < 64 * 28; idx += 256) {
        int r = idx / 28, j = idx - r * 28;
        As[r * 29 + j] = Qv[((q0 + r) * NH + h) * QKD + j];
        Bs[r * 29 + j] = Kv[((k0 + r) * NH + h) * QKD + j];
    }
    __syncthreads();
    float c[4][4] = {};
    #pragma unroll
    for (int kk = 0; kk < 28; ++kk) {
        float a[4], b[4];
        #pragma unroll
        for (int i = 0; i < 4; ++i) a[i] = As[(ty * 4 + i) * 29 + kk];
        #pragma unroll
        for (int j = 0; j < 4; ++j) b[j] = Bs[(tx * 4 + j) * 29 + kk];
        #pragma unroll
        for (int i = 0; i < 4; ++i)
            #pragma unroll
            for (int j = 0; j < 4; ++j) c[i][j] += a[i] * b[j];
    }
    float akv[4];
    #pragma unroll
    for (int j = 0; j < 4; ++j) akv[j] = akArr[(k0 + tx * 4 + j) * NH + h];
    #pragma unroll
    for (int i = 0; i < 4; ++i) {
        float4 v;
        v.x = c[i][0] + akv[0]; v.y = c[i][1] + akv[1];
        v.z = c[i][2] + akv[2]; v.w = c[i][3] + akv[3];
        *(float4*)&qkBuf[((q0 + ty * 4 + i) * NH + h) * NRES + k0 + tx * 4] = v;
    }
}

// ---------------------------------------------------------------------------
// KA: qkBuf[q][h][k] = (qkBuf + act2d[q,k,:].w2d[:,h] + mask) * sqrt(1/3)
//   grid (12 k-tiles, 768 q).  Thread = (row r, head-triple g).
//   w2d read as same-address wave broadcasts (whole wave shares g).
// ---------------------------------------------------------------------------
__global__ __launch_bounds__(256) void kA_bias(
    const float* __restrict__ act2d, const float* __restrict__ smask,
    const float* __restrict__ w2d, float* __restrict__ qkBuf)
{
    const int q = blockIdx.y, k0 = blockIdx.x * 64, tid = threadIdx.x;
    __shared__ float tile[64 * 132];   // 33.8 KB, rows padded
    __shared__ float w2dS[NH * 128];   // [h][c], 6 KB

    for (int idx = tid; idx < C2V * NH; idx += 256)
        w2dS[(idx % NH) * 128 + (idx / NH)] = w2d[idx];
    const float* src = act2d + ((size_t)q * NRES + k0) * C2V;
    #pragma unroll
    for (int i = 0; i < 8; ++i) {
        int f = tid + i * 256;
        float4 v = ((const float4*)src)[f];
        int r = f >> 5, cq = f & 31;
        *(float4*)&tile[r * 132 + cq * 4] = v;
    }
    __syncthreads();

    const int r = tid & 63, g = tid >> 6;        // heads 3g..3g+2
    const float* trow = &tile[r * 132];
    const float* w0 = &w2dS[(3 * g    ) * 128];
    const float* w1 = &w2dS[(3 * g + 1) * 128];
    const float* w2 = &w2dS[(3 * g + 2) * 128];
    float4 A0 = {0,0,0,0}, A1 = {0,0,0,0}, A2 = {0,0,0,0};
    #pragma unroll
    for (int c = 0; c < 128; c += 4) {
        float4 t  = *(const float4*)&trow[c];
        float4 x0 = *(const float4*)&w0[c];
        float4 x1 = *(const float4*)&w1[c];
        float4 x2 = *(const float4*)&w2[c];
        A0.x += t.x * x0.x; A0.y += t.y * x0.y; A0.z += t.z * x0.z; A0.w += t.w * x0.w;
        A1.x += t.x * x1.x; A1.y += t.y * x1.y; A1.z += t.z * x1.z; A1.w += t.w * x1.w;
        A2.x += t.x * x2.x; A2.y += t.y * x2.y; A2.z += t.z * x2.z; A2.w += t.w * x2.w;
    }
    float d0 = A0.x + A0.y + A0.z + A0.w;
    float d1 = A1.x + A1.y + A1.z + A1.w;
    float d2 = A2.x + A2.y + A2.z + A2.w;
    const int k = k0 + r;
    const float msk = -1e5f * (1.f - smask[q] * smask[k]);
    const float scale = 0.5773502691896258f;     // sqrt(1/3)
    size_t i0 = ((size_t)(q * NH + 3 * g    )) * NRES + k;
    size_t i1 = ((size_t)(q * NH + 3 * g + 1)) * NRES + k;
    size_t i2 = ((size_t)(q * NH + 3 * g + 2)) * NRES + k;
    qkBuf[i0] = (qkBuf[i0] + d0 + msk) * scale;
    qkBuf[i1] = (qkBuf[i1] + d1 + msk) * scale;
    qkBuf[i2] = (qkBuf[i2] + d2 + msk) * scale;
}

// ---------------------------------------------------------------------------
// KC: per-q softmax (unnormalized exp in LDS, 1/l folded into epilogues)
//     + r2d as LDS-tiled GEMM (24-row act2d slabs)
//     + vv pass (float4 columns, one head per column, L2-resident vv).
//   LDS ~49.7 KB -> 3 blocks/CU.  NO min-waves bound (avoid spills).
// ---------------------------------------------------------------------------
__global__ __launch_bounds__(256) void kC_attn(
    const float* __restrict__ act2d, const float* __restrict__ qkBuf,
    const float* __restrict__ vv, const float* __restrict__ rot,
    const float* __restrict__ trans, float* __restrict__ F)
{
    const int q = blockIdx.x, tid = threadIdx.x;
    __shared__ float attnS[NH * APAD];     // 37.1 KB, unnormalized exp
    __shared__ float tile[24 * 128];       // 12 KB slab / scratch
    __shared__ float red[NH * 4];
    __shared__ float mh[NH], lh[NH];
    __shared__ float rotS[9], transS[3];

    if (tid < 9) rotS[tid] = rot[q * 9 + tid];
    if (tid < 3) transS[tid] = trans[q * 3 + tid];

    // ---- logits (masked+scaled by kA) ----
    float lg[3][NH];
    #pragma unroll
    for (int h = 0; h < NH; ++h)
        #pragma unroll
        for (int i = 0; i < 3; ++i)
            lg[i][h] = qkBuf[((size_t)(q * NH + h)) * NRES + tid + 256 * i];

    // ---- softmax over k ----
    const int wv_ = tid >> 6, lane = tid & 63;
    #pragma unroll
    for (int h = 0; h < NH; ++h) {
        float v = fmaxf(fmaxf(lg[0][h], lg[1][h]), lg[2][h]);
        for (int off = 32; off > 0; off >>= 1) v = fmaxf(v, __shfl_down(v, off, 64));
        if (lane == 0) red[h * 4 + wv_] = v;
    }
    __syncthreads();
    if (tid < NH)
        mh[tid] = fmaxf(fmaxf(red[tid * 4], red[tid * 4 + 1]),
                        fmaxf(red[tid * 4 + 2], red[tid * 4 + 3]));
    __syncthreads();
    float lsum[NH];
    #pragma unroll
    for (int h = 0; h < NH; ++h) lsum[h] = 0.f;
    #pragma unroll
    for (int i = 0; i < 3; ++i)
        #pragma unroll
        for (int h = 0; h < NH; ++h) {
            float e = __expf(lg[i][h] - mh[h]);
            attnS[h * APAD + tid + 256 * i] = e;
            lsum[h] += e;
        }
    #pragma unroll
    for (int h = 0; h < NH; ++h) {
        float v = lsum[h];
        for (int off = 32; off > 0; off >>= 1) v += __shfl_down(v, off, 64);
        if (lane == 0) red[h * 4 + wv_] = v;
    }
    __syncthreads();
    if (tid < NH)
        lh[tid] = 1.f / (red[tid * 4] + red[tid * 4 + 1] + red[tid * 4 + 2] + red[tid * 4 + 3]);

    // ---- r2d: C[12][128] = attn[12][768] x act2d_q[768][128] ----
    const int c = tid & 127, kg = tid >> 7;     // kg in {0,1}: k-halves of each slab
    float acc[NH];
    #pragma unroll
    for (int h = 0; h < NH; ++h) acc[h] = 0.f;

    for (int s = 0; s < 32; ++s) {
        const int k0 = s * 24;
        __syncthreads();
        const float* src = act2d + ((size_t)q * NRES + k0) * C2V;
        #pragma unroll
        for (int i = 0; i < 3; ++i) {
            int f = tid + i * 256;
            ((float4*)tile)[f] = ((const float4*)src)[f];
        }
        __syncthreads();
        #pragma unroll
        for (int k4 = 0; k4 < 3; ++k4) {
            const int kb = kg * 12 + k4 * 4;
            float4 av[NH];
            #pragma unroll
            for (int h = 0; h < NH; ++h)
                av[h] = *(const float4*)&attnS[h * APAD + k0 + kb];
            #pragma unroll
            for (int u = 0; u < 4; ++u) {
                float t = tile[(kb + u) * 128 + c];
                #pragma unroll
                for (int h = 0; h < NH; ++h)
                    acc[h] += ((const float*)&av[h])[u] * t;
            }
        }
    }
    __syncthreads();
    if (kg == 1) {
        #pragma unroll
        for (int h = 0; h < NH; ++h) tile[h * 128 + c] = acc[h];
    }
    __syncthreads();
    float* Fq = F + q * FDIM;
    if (kg == 0) {
        #pragma unroll
        for (int h = 0; h < NH; ++h)
            Fq[576 + h * 128 + c] = (acc[h] + tile[h * 128 + c]) * lh[h];
    }
    __syncthreads();

    // ---- vv pass: out[j] = sum_k attn[hmap(j)][k] * vv[k][j], j in [0,480) ----
    // float4 columns j4 in [0,120); each float4 column has one head.
    const int j4 = tid & 127;                    // active if j4 < 120
    const int kgv = tid >> 7;
    float p0 = 0.f, p1 = 0.f, p2 = 0.f, p3 = 0.f;
    if (j4 < 120) {
        const int h = (j4 < 48) ? (j4 >> 2) : ((j4 - 48) / 6);
        const float* at = &attnS[h * APAD + kgv * 384];
        const float* col = vv + (size_t)(kgv * 384) * VVD + j4 * 4;
        #pragma unroll 4
        for (int k = 0; k < 384; ++k) {
            float a = at[k];
            float4 v = *(const float4*)(col + (size_t)k * VVD);
            p0 += a * v.x; p1 += a * v.y; p2 += a * v.z; p3 += a * v.w;
        }
    }
    __syncthreads();
    if (j4 < 120) {
        float4 pv = {p0, p1, p2, p3};
        *(float4*)&tile[(kgv * 120 + j4) * 4] = pv;
    }
    __syncthreads();
    if (tid < 120) {
        float4 a = *(const float4*)&tile[tid * 4];
        float4 b = *(const float4*)&tile[(120 + tid) * 4];
        const int h = (tid < 48) ? (tid >> 2) : ((tid - 48) / 6);
        const float il = lh[h];
        float4 s = {(a.x + b.x) * il, (a.y + b.y) * il,
                    (a.z + b.z) * il, (a.w + b.w) * il};
        if (tid < 48) {
            *(float4*)&Fq[tid * 4] = s;                 // res_scalar (192)
        } else {
            *(float4*)&tile[1024 + (tid - 48) * 4] = s; // rpg (288) -> scratch
        }
    }
    __syncthreads();
    if (tid < 96) {
        float gx = tile[1024 + tid * 3]     - transS[0];
        float gy = tile[1024 + tid * 3 + 1] - transS[1];
        float gz = tile[1024 + tid * 3 + 2] - transS[2];
        // invert_apply: rpl_i = sum_j R[j][i] * g_j
        float x = rotS[0] * gx + rotS[3] * gy + rotS[6] * gz;
        float y = rotS[1] * gx + rotS[4] * gy + rotS[7] * gz;
        float z = rotS[2] * gx + rotS[5] * gy + rotS[8] * gz;
        Fq[192 + tid] = x;
        Fq[288 + tid] = y;
        Fq[384 + tid] = z;
        Fq[480 + tid] = sqrtf(x * x + y * y + z * z);
    }
}

// ---------------------------------------------------------------------------
// K5: out = F @ wfin + bfin.  M=768, N=384, K=2112. No atomics.
// ---------------------------------------------------------------------------
__global__ __launch_bounds__(256) void k5_final(
    const float* __restrict__ F, const float* __restrict__ wfin,
    const float* __restrict__ bfin, float* __restrict__ out)
{
    const int n0 = blockIdx.x * 32, m0 = blockIdx.y * 64;
    __shared__ float As[64 * 33];
    __shared__ float Bs[32 * 36];
    const int tid = threadIdx.x, tx = tid & 7, ty = tid >> 3;
    float c0_[4] = {}, c1_[4] = {};

    for (int kt = 0; kt < FDIM; kt += 32) {
        for (int idx = tid; idx < 64 * 32; idx += 256) {
            int r = idx >> 5, j = idx & 31;
            As[r * 33 + j] = F[(m0 + r) * FDIM + kt + j];
        }
        for (int idx = tid; idx < 32 * 32; idx += 256) {
            int r = idx >> 5, col = idx & 31;
            Bs[r * 36 + col] = wfin[(kt + r) * 384 + n0 + col];
        }
        __syncthreads();
        #pragma unroll
        for (int kk = 0; kk < 32; ++kk) {
            float a0 = As[(ty * 2) * 33 + kk];
            float a1 = As[(ty * 2 + 1) * 33 + kk];
            float4 b = *(const float4*)&Bs[kk * 36 + tx * 4];
            c0_[0] += a0 * b.x; c0_[1] += a0 * b.y; c0_[2] += a0 * b.z; c0_[3] += a0 * b.w;
            c1_[0] += a1 * b.x; c1_[1] += a1 * b.y; c1_[2] += a1 * b.z; c1_[3] += a1 * b.w;
        }
        __syncthreads();
    }
    float4 bias = *(const float4*)&bfin[n0 + tx * 4];
    float4 v0 = {c0_[0] + bias.x, c0_[1] + bias.y, c0_[2] + bias.z, c0_[3] + bias.w};
    float4 v1 = {c1_[0] + bias.x, c1_[1] + bias.y, c1_[2] + bias.z, c1_[3] + bias.w};
    *(float4*)&out[(m0 + ty * 2) * 384 + n0 + tx * 4] = v0;
    *(float4*)&out[(m0 + ty * 2 + 1) * 384 + n0 + tx * 4] = v1;
}

// ---------------------------------------------------------------------------
extern "C" void kernel_launch(void* const* d_in, const int* in_sizes, int n_in,
                              void* d_out, int out_size, void* d_ws, size_t ws_size,
                              hipStream_t stream) {
    const float* act   = (const float*)d_in[0];
    const float* act2d = (const float*)d_in[1];
    const float* smask = (const float*)d_in[2];
    const float* rot   = (const float*)d_in[3];
    const float* trans = (const float*)d_in[4];
    const float* wq    = (const float*)d_in[5];
    const float* wk    = (const float*)d_in[6];
    const float* wvv   = (const float*)d_in[7];
    const float* wqp   = (const float*)d_in[8];
    const float* bqp   = (const float*)d_in[9];
    const float* wkp   = (const float*)d_in[10];
    const float* bkp   = (const float*)d_in[11];
    const float* wvp   = (const float*)d_in[12];
    const float* bvp   = (const float*)d_in[13];
    const float* w2d   = (const float*)d_in[14];
    // d_in[15] = b2d: constant over k, cancels in softmax over k -> unused
    const float* wfin  = (const float*)d_in[16];
    const float* bfin  = (const float*)d_in[17];
    const float* tw    = (const float*)d_in[18];

    float* W     = (float*)d_ws;
    float* proj  = W;                      // 768*1152
    float* Qv    = proj  + 768 * NPROJ;    // 768*12*28
    float* Kv    = Qv    + 768 * NH * QKD;
    float* akArr = Kv    + 768 * NH * QKD; // 768*12
    float* vvA   = akArr + 768 * NH;       // 768*480
    float* qkBuf = vvA   + 768 * VVD;      // 768*12*768
    float* F     = qkBuf + 768 * NH * NRES;// 768*2112

    k1_proj<<<dim3(18, 12), 256, 0, stream>>>(act, wq, wk, wvv, wqp, wkp, wvp,
                                              bqp, bkp, bvp, proj);
    k2_prep<<<dim3(NRES), 64, 0, stream>>>(proj, rot, trans, tw, Qv, Kv, akArr, vvA);
    k2b_qk<<<dim3(12, 12, NH), 256, 0, stream>>>(Qv, Kv, akArr, qkBuf);
    kA_bias<<<dim3(12, NRES), 256, 0, stream>>>(act2d, smask, w2d, qkBuf);
    kC_attn<<<dim3(NRES), 256, 0, stream>>>(act2d, qkBuf, vvA, rot, trans, F);
    k5_final<<<dim3(12, 12), 256, 0, stream>>>(F, wfin, bfin, (float*)d_out);
}

// Round 4
// 708.721 us; speedup vs baseline: 3.8383x; 1.2740x over previous
//
#include <hip/hip_runtime.h>
#include <math.h>

// Problem constants (B=1)
#define NH    12      // heads
#define NRES  768     // sequence length
#define C1V   384
#define C2V   128
#define NPROJ 1152    // 192+192+192+144+144+288
#define QKD   28      // 16 scalar + 12 point dims
#define FDIM  2112    // 192 + 3*96 + 96 + 1536
#define VVD   480     // 192 (v) + 288 (vp global)
#define APAD  772     // attn row pad: (h*772+k)%32 = (4h+k)%32 -> no 12-way alias
#define KSPLIT 11     // k5 split-K factor (2112 = 11 * 192)

__device__ __forceinline__ float softplusf_(float x) {
    return (x > 20.f) ? x : log1pf(__expf(x));
}

// ---------------------------------------------------------------------------
// K1: proj = act @ [wq|wk|wv|wqp|wkp|wvp] + [0|0|0|bqp|bkp|bvp]
// ---------------------------------------------------------------------------
__global__ __launch_bounds__(256) void k1_proj(
    const float* __restrict__ act,
    const float* __restrict__ wq, const float* __restrict__ wk,
    const float* __restrict__ wv, const float* __restrict__ wqp,
    const float* __restrict__ wkp, const float* __restrict__ wvp,
    const float* __restrict__ bqp, const float* __restrict__ bkp,
    const float* __restrict__ bvp, float* __restrict__ proj)
{
    __shared__ float As[64 * 33];
    __shared__ float Bs[32 * 65];
    const int n0 = blockIdx.x * 64, m0 = blockIdx.y * 64;
    const int tid = threadIdx.x;
    const int tx = tid & 15, ty = tid >> 4;
    float c[4][4] = {};

    for (int kt = 0; kt < C1V; kt += 32) {
        for (int idx = tid; idx < 64 * 32; idx += 256) {
            int r = idx >> 5, j = idx & 31;
            As[r * 33 + j] = act[(m0 + r) * C1V + kt + j];
        }
        for (int idx = tid; idx < 32 * 64; idx += 256) {
            int r = idx >> 6, col = idx & 63;
            int jj = n0 + col, k = kt + r;
            float w;
            if      (jj < 192) w = wq [k * 192 + jj];
            else if (jj < 384) w = wk [k * 192 + jj - 192];
            else if (jj < 576) w = wv [k * 192 + jj - 384];
            else if (jj < 720) w = wqp[k * 144 + jj - 576];
            else if (jj < 864) w = wkp[k * 144 + jj - 720];
            else               w = wvp[k * 288 + jj - 864];
            Bs[r * 65 + col] = w;
        }
        __syncthreads();
        #pragma unroll
        for (int kk = 0; kk < 32; ++kk) {
            float a[4], b[4];
            #pragma unroll
            for (int i = 0; i < 4; ++i) a[i] = As[(ty * 4 + i) * 33 + kk];
            #pragma unroll
            for (int j = 0; j < 4; ++j) b[j] = Bs[kk * 65 + tx * 4 + j];
            #pragma unroll
            for (int i = 0; i < 4; ++i)
                #pragma unroll
                for (int j = 0; j < 4; ++j) c[i][j] += a[i] * b[j];
        }
        __syncthreads();
    }
    float biasv[4];
    #pragma unroll
    for (int j = 0; j < 4; ++j) {
        int col = n0 + tx * 4 + j;
        biasv[j] = (col >= 864) ? bvp[col - 864]
                 : (col >= 720) ? bkp[col - 720]
                 : (col >= 576) ? bqp[col - 576] : 0.f;
    }
    #pragma unroll
    for (int i = 0; i < 4; ++i) {
        float4 v;
        v.x = c[i][0] + biasv[0]; v.y = c[i][1] + biasv[1];
        v.z = c[i][2] + biasv[2]; v.w = c[i][3] + biasv[3];
        *(float4*)&proj[(m0 + ty * 4 + i) * NPROJ + n0 + tx * 4] = v;
    }
}

// ---------------------------------------------------------------------------
// K2: per-residue prep. Qv[n][h][28] (q*0.25 | pw*qp_glob), Kv[n][h][28],
//     ak[n][h] = -0.5*pw*sum|kp|^2, vv[n][480] = [v(192) | vp_global(288)].
// ---------------------------------------------------------------------------
__global__ __launch_bounds__(64) void k2_prep(
    const float* __restrict__ proj, const float* __restrict__ rot,
    const float* __restrict__ trans, const float* __restrict__ tw,
    float* __restrict__ Qv, float* __restrict__ Kv,
    float* __restrict__ akArr, float* __restrict__ vv)
{
    const int n = blockIdx.x, tid = threadIdx.x;
    __shared__ float kp2[48];
    const float* pr = proj + n * NPROJ;
    float R[9], T[3];
    #pragma unroll
    for (int i = 0; i < 9; ++i) R[i] = rot[n * 9 + i];
    #pragma unroll
    for (int i = 0; i < 3; ++i) T[i] = trans[n * 3 + i];

    for (int idx = tid; idx < 192; idx += 64) {
        int h = idx >> 4, cc = idx & 15;
        Qv[(n * NH + h) * QKD + cc] = pr[idx] * 0.25f;          // sqrt(1/16)
        Kv[(n * NH + h) * QKD + cc] = pr[192 + idx];
        vv[n * VVD + idx] = pr[384 + idx];                      // v
    }
    if (tid < 48) {
        int h = tid >> 2, p = tid & 3;
        float pwh = 0.23570226039551584f * softplusf_(tw[h]);   // sqrt(2/36)*softplus
        float lx = pr[576 + h * 12 + p];
        float ly = pr[576 + h * 12 + 4 + p];
        float lz = pr[576 + h * 12 + 8 + p];
        float gx = R[0] * lx + R[1] * ly + R[2] * lz + T[0];
        float gy = R[3] * lx + R[4] * ly + R[5] * lz + T[1];
        float gz = R[6] * lx + R[7] * ly + R[8] * lz + T[2];
        float* qd = &Qv[(n * NH + h) * QKD + 16];
        qd[p] = pwh * gx; qd[4 + p] = pwh * gy; qd[8 + p] = pwh * gz;
        lx = pr[720 + h * 12 + p];
        ly = pr[720 + h * 12 + 4 + p];
        lz = pr[720 + h * 12 + 8 + p];
        gx = R[0] * lx + R[1] * ly + R[2] * lz + T[0];
        gy = R[3] * lx + R[4] * ly + R[5] * lz + T[1];
        gz = R[6] * lx + R[7] * ly + R[8] * lz + T[2];
        float* kd = &Kv[(n * NH + h) * QKD + 16];
        kd[p] = gx; kd[4 + p] = gy; kd[8 + p] = gz;
        kp2[tid] = gx * gx + gy * gy + gz * gz;
    }
    __syncthreads();
    if (tid < NH) {
        float pwh = 0.23570226039551584f * softplusf_(tw[tid]);
        akArr[n * NH + tid] = -0.5f * pwh *
            (kp2[tid * 4] + kp2[tid * 4 + 1] + kp2[tid * 4 + 2] + kp2[tid * 4 + 3]);
    }
    for (int idx = tid; idx < 96; idx += 64) {
        int h = idx >> 3, p = idx & 7;
        float lx = pr[864 + h * 24 + p];
        float ly = pr[864 + h * 24 + 8 + p];
        float lz = pr[864 + h * 24 + 16 + p];
        float gx = R[0] * lx + R[1] * ly + R[2] * lz + T[0];
        float gy = R[3] * lx + R[4] * ly + R[5] * lz + T[1];
        float gz = R[6] * lx + R[7] * ly + R[8] * lz + T[2];
        float* dst = &vv[n * VVD + 192 + h * 24 + p * 3];
        dst[0] = gx; dst[1] = gy; dst[2] = gz;
    }
}

// ---------------------------------------------------------------------------
// K2b: qkBuf[q][h][k] = Qv[q,h,:].Kv[k,h,:] + ak[k,h]
// ---------------------------------------------------------------------------
__global__ __launch_bounds__(256) void k2b_qk(
    const float* __restrict__ Qv, const float* __restrict__ Kv,
    const float* __restrict__ akArr, float* __restrict__ qkBuf)
{
    const int h = blockIdx.z;
    const int k0 = blockIdx.x * 64, q0 = blockIdx.y * 64;
    __shared__ float As[64 * 29];
    __shared__ float Bs[64 * 29];
    const int tid = threadIdx.x, tx = tid & 15, ty = tid >> 4;

    for (int idx = tid; idx < 64 * 28; idx += 256) {
        int r = idx / 28, j = idx - r * 28;
        As[r * 29 + j] = Qv[((q0 + r) * NH + h) * QKD + j];
        Bs[r * 29 + j] = Kv[((k0 + r) * NH + h) * QKD + j];
    }
    __syncthreads();
    float c[4][4] = {};
    #pragma unroll
    for (int kk = 0; kk < 28; ++kk) {
        float a[4], b[4];
        #pragma unroll
        for (int i = 0; i < 4; ++i) a[i] = As[(ty * 4 + i) * 29 + kk];
        #pragma unroll
        for (int j = 0; j < 4; ++j) b[j] = Bs[(tx * 4 + j) * 29 + kk];
        #pragma unroll
        for (int i = 0; i < 4; ++i)
            #pragma unroll
            for (int j = 0; j < 4; ++j) c[i][j] += a[i] * b[j];
    }
    float akv[4];
    #pragma unroll
    for (int j = 0; j < 4; ++j) akv[j] = akArr[(k0 + tx * 4 + j) * NH + h];
    #pragma unroll
    for (int i = 0; i < 4; ++i) {
        float4 v;
        v.x = c[i][0] + akv[0]; v.y = c[i][1] + akv[1];
        v.z = c[i][2] + akv[2]; v.w = c[i][3] + akv[3];
        *(float4*)&qkBuf[((q0 + ty * 4 + i) * NH + h) * NRES + k0 + tx * 4] = v;
    }
}

// ---------------------------------------------------------------------------
// KA: qkBuf[q][h][k] = (qkBuf + act2d[q,k,:].w2d[:,h] + mask) * sqrt(1/3)
//   grid (12 k-tiles, 768 q).  Thread = (row r, head-triple g).
//   Tile stride 129 (odd): scalar reads bank = (lane + c) % 32 -> conflict-free.
//   w2d reads are same-address wave broadcasts (free).
// ---------------------------------------------------------------------------
__global__ __launch_bounds__(256) void kA_bias(
    const float* __restrict__ act2d, const float* __restrict__ smask,
    const float* __restrict__ w2d, float* __restrict__ qkBuf)
{
    const int q = blockIdx.y, k0 = blockIdx.x * 64, tid = threadIdx.x;
    __shared__ float tile[64 * 129];   // 33 KB, odd row stride
    __shared__ float w2dS[NH * 128];   // [h][c], 6 KB

    for (int idx = tid; idx < C2V * NH; idx += 256)
        w2dS[(idx % NH) * 128 + (idx / NH)] = w2d[idx];
    const float* src = act2d + ((size_t)q * NRES + k0) * C2V;
    #pragma unroll
    for (int i = 0; i < 8; ++i) {
        int f = tid + i * 256;
        float4 v = ((const float4*)src)[f];
        int r = f >> 5, cq = f & 31;
        float* dst = &tile[r * 129 + cq * 4];
        dst[0] = v.x; dst[1] = v.y; dst[2] = v.z; dst[3] = v.w;
    }
    __syncthreads();

    const int r = tid & 63, g = tid >> 6;        // heads 3g..3g+2
    const float* trow = &tile[r * 129];
    const float* w0 = &w2dS[(3 * g    ) * 128];
    const float* w1 = &w2dS[(3 * g + 1) * 128];
    const float* w2 = &w2dS[(3 * g + 2) * 128];
    float d0 = 0.f, d1 = 0.f, d2 = 0.f;
    #pragma unroll
    for (int c = 0; c < 128; ++c) {
        float t = trow[c];
        d0 += t * w0[c];
        d1 += t * w1[c];
        d2 += t * w2[c];
    }
    const int k = k0 + r;
    const float msk = -1e5f * (1.f - smask[q] * smask[k]);
    const float scale = 0.5773502691896258f;     // sqrt(1/3)
    size_t i0 = ((size_t)(q * NH + 3 * g    )) * NRES + k;
    size_t i1 = ((size_t)(q * NH + 3 * g + 1)) * NRES + k;
    size_t i2 = ((size_t)(q * NH + 3 * g + 2)) * NRES + k;
    qkBuf[i0] = (qkBuf[i0] + d0 + msk) * scale;
    qkBuf[i1] = (qkBuf[i1] + d1 + msk) * scale;
    qkBuf[i2] = (qkBuf[i2] + d2 + msk) * scale;
}

// ---------------------------------------------------------------------------
// KC: per-q softmax (unnormalized exp in LDS, 1/l folded into epilogues)
//     + r2d as LDS-tiled GEMM (24-row act2d slabs)
//     + vv pass (float4 columns, one head per column, L2-resident vv).
//   LDS ~49.7 KB -> 3 blocks/CU.  NO min-waves bound (avoid spills).
// ---------------------------------------------------------------------------
__global__ __launch_bounds__(256) void kC_attn(
    const float* __restrict__ act2d, const float* __restrict__ qkBuf,
    const float* __restrict__ vv, const float* __restrict__ rot,
    const float* __restrict__ trans, float* __restrict__ F)
{
    const int q = blockIdx.x, tid = threadIdx.x;
    __shared__ float attnS[NH * APAD];     // 37.1 KB, unnormalized exp
    __shared__ float tile[24 * 128];       // 12 KB slab / scratch
    __shared__ float red[NH * 4];
    __shared__ float mh[NH], lh[NH];
    __shared__ float rotS[9], transS[3];

    if (tid < 9) rotS[tid] = rot[q * 9 + tid];
    if (tid < 3) transS[tid] = trans[q * 3 + tid];

    // ---- logits (masked+scaled by kA) ----
    float lg[3][NH];
    #pragma unroll
    for (int h = 0; h < NH; ++h)
        #pragma unroll
        for (int i = 0; i < 3; ++i)
            lg[i][h] = qkBuf[((size_t)(q * NH + h)) * NRES + tid + 256 * i];

    // ---- softmax over k ----
    const int wv_ = tid >> 6, lane = tid & 63;
    #pragma unroll
    for (int h = 0; h < NH; ++h) {
        float v = fmaxf(fmaxf(lg[0][h], lg[1][h]), lg[2][h]);
        for (int off = 32; off > 0; off >>= 1) v = fmaxf(v, __shfl_down(v, off, 64));
        if (lane == 0) red[h * 4 + wv_] = v;
    }
    __syncthreads();
    if (tid < NH)
        mh[tid] = fmaxf(fmaxf(red[tid * 4], red[tid * 4 + 1]),
                        fmaxf(red[tid * 4 + 2], red[tid * 4 + 3]));
    __syncthreads();
    float lsum[NH];
    #pragma unroll
    for (int h = 0; h < NH; ++h) lsum[h] = 0.f;
    #pragma unroll
    for (int i = 0; i < 3; ++i)
        #pragma unroll
        for (int h = 0; h < NH; ++h) {
            float e = __expf(lg[i][h] - mh[h]);
            attnS[h * APAD + tid + 256 * i] = e;
            lsum[h] += e;
        }
    #pragma unroll
    for (int h = 0; h < NH; ++h) {
        float v = lsum[h];
        for (int off = 32; off > 0; off >>= 1) v += __shfl_down(v, off, 64);
        if (lane == 0) red[h * 4 + wv_] = v;
    }
    __syncthreads();
    if (tid < NH)
        lh[tid] = 1.f / (red[tid * 4] + red[tid * 4 + 1] + red[tid * 4 + 2] + red[tid * 4 + 3]);

    // ---- r2d: C[12][128] = attn[12][768] x act2d_q[768][128] ----
    const int c = tid & 127, kg = tid >> 7;     // kg in {0,1}: k-halves of each slab
    float acc[NH];
    #pragma unroll
    for (int h = 0; h < NH; ++h) acc[h] = 0.f;

    for (int s = 0; s < 32; ++s) {
        const int k0 = s * 24;
        __syncthreads();
        const float* src = act2d + ((size_t)q * NRES + k0) * C2V;
        #pragma unroll
        for (int i = 0; i < 3; ++i) {
            int f = tid + i * 256;
            ((float4*)tile)[f] = ((const float4*)src)[f];
        }
        __syncthreads();
        #pragma unroll
        for (int k4 = 0; k4 < 3; ++k4) {
            const int kb = kg * 12 + k4 * 4;
            float4 av[NH];
            #pragma unroll
            for (int h = 0; h < NH; ++h)
                av[h] = *(const float4*)&attnS[h * APAD + k0 + kb];
            #pragma unroll
            for (int u = 0; u < 4; ++u) {
                float t = tile[(kb + u) * 128 + c];
                #pragma unroll
                for (int h = 0; h < NH; ++h)
                    acc[h] += ((const float*)&av[h])[u] * t;
            }
        }
    }
    __syncthreads();
    if (kg == 1) {
        #pragma unroll
        for (int h = 0; h < NH; ++h) tile[h * 128 + c] = acc[h];
    }
    __syncthreads();
    float* Fq = F + q * FDIM;
    if (kg == 0) {
        #pragma unroll
        for (int h = 0; h < NH; ++h)
            Fq[576 + h * 128 + c] = (acc[h] + tile[h * 128 + c]) * lh[h];
    }
    __syncthreads();

    // ---- vv pass: out[j] = sum_k attn[hmap(j)][k] * vv[k][j], j in [0,480) ----
    const int j4 = tid & 127;                    // active if j4 < 120
    const int kgv = tid >> 7;
    float p0 = 0.f, p1 = 0.f, p2 = 0.f, p3 = 0.f;
    if (j4 < 120) {
        const int h = (j4 < 48) ? (j4 >> 2) : ((j4 - 48) / 6);
        const float* at = &attnS[h * APAD + kgv * 384];
        const float* col = vv + (size_t)(kgv * 384) * VVD + j4 * 4;
        #pragma unroll 4
        for (int k = 0; k < 384; ++k) {
            float a = at[k];
            float4 v = *(const float4*)(col + (size_t)k * VVD);
            p0 += a * v.x; p1 += a * v.y; p2 += a * v.z; p3 += a * v.w;
        }
    }
    __syncthreads();
    if (j4 < 120) {
        float4 pv = {p0, p1, p2, p3};
        *(float4*)&tile[(kgv * 120 + j4) * 4] = pv;
    }
    __syncthreads();
    if (tid < 120) {
        float4 a = *(const float4*)&tile[tid * 4];
        float4 b = *(const float4*)&tile[(120 + tid) * 4];
        const int h = (tid < 48) ? (tid >> 2) : ((tid - 48) / 6);
        const float il = lh[h];
        float4 s = {(a.x + b.x) * il, (a.y + b.y) * il,
                    (a.z + b.z) * il, (a.w + b.w) * il};
        if (tid < 48) {
            *(float4*)&Fq[tid * 4] = s;                 // res_scalar (192)
        } else {
            *(float4*)&tile[1024 + (tid - 48) * 4] = s; // rpg (288) -> scratch
        }
    }
    __syncthreads();
    if (tid < 96) {
        float gx = tile[1024 + tid * 3]     - transS[0];
        float gy = tile[1024 + tid * 3 + 1] - transS[1];
        float gz = tile[1024 + tid * 3 + 2] - transS[2];
        // invert_apply: rpl_i = sum_j R[j][i] * g_j
        float x = rotS[0] * gx + rotS[3] * gy + rotS[6] * gz;
        float y = rotS[1] * gx + rotS[4] * gy + rotS[7] * gz;
        float z = rotS[2] * gx + rotS[5] * gy + rotS[8] * gz;
        Fq[192 + tid] = x;
        Fq[288 + tid] = y;
        Fq[384 + tid] = z;
        Fq[480 + tid] = sqrtf(x * x + y * y + z * z);
    }
}

// ---------------------------------------------------------------------------
// K5: split-K partials.  part[kz][m][n] = F[m, kz*192:(kz+1)*192] @ wfin slice.
//     grid (6 n-tiles, 12 m-tiles, 11 kz) = 792 blocks, 6 K-iters each.
// ---------------------------------------------------------------------------
__global__ __launch_bounds__(256) void k5_partial(
    const float* __restrict__ F, const float* __restrict__ wfin,
    float* __restrict__ part)
{
    const int n0 = blockIdx.x * 64, m0 = blockIdx.y * 64, kz = blockIdx.z;
    const int kbeg = kz * 192;
    __shared__ float As[64 * 33];
    __shared__ float Bs[32 * 65];
    const int tid = threadIdx.x, tx = tid & 15, ty = tid >> 4;
    float c[4][4] = {};

    for (int kt = kbeg; kt < kbeg + 192; kt += 32) {
        for (int idx = tid; idx < 64 * 32; idx += 256) {
            int r = idx >> 5, j = idx & 31;
            As[r * 33 + j] = F[(m0 + r) * FDIM + kt + j];
        }
        for (int idx = tid; idx < 32 * 64; idx += 256) {
            int r = idx >> 6, col = idx & 63;
            Bs[r * 65 + col] = wfin[(kt + r) * 384 + n0 + col];
        }
        __syncthreads();
        #pragma unroll
        for (int kk = 0; kk < 32; ++kk) {
            float a[4], b[4];
            #pragma unroll
            for (int i = 0; i < 4; ++i) a[i] = As[(ty * 4 + i) * 33 + kk];
            #pragma unroll
            for (int j = 0; j < 4; ++j) b[j] = Bs[kk * 65 + tx * 4 + j];
            #pragma unroll
            for (int i = 0; i < 4; ++i)
                #pragma unroll
                for (int j = 0; j < 4; ++j) c[i][j] += a[i] * b[j];
        }
        __syncthreads();
    }
    float* dst = part + (size_t)kz * (768 * 384);
    #pragma unroll
    for (int i = 0; i < 4; ++i) {
        float4 v = {c[i][0], c[i][1], c[i][2], c[i][3]};
        *(float4*)&dst[(m0 + ty * 4 + i) * 384 + n0 + tx * 4] = v;
    }
}

// ---------------------------------------------------------------------------
// K5r: out[m][n] = bias[n] + sum_kz part[kz][m][n].  float4-granular.
// ---------------------------------------------------------------------------
__global__ __launch_bounds__(256) void k5_reduce(
    const float* __restrict__ part, const float* __restrict__ bfin,
    float* __restrict__ out)
{
    const int e = blockIdx.x * 256 + threadIdx.x;      // float4 index, 73728 total
    const float4* p = (const float4*)part;
    float4 b = ((const float4*)bfin)[e % 96];
    float4 s = {b.x, b.y, b.z, b.w};
    #pragma unroll
    for (int kz = 0; kz < KSPLIT; ++kz) {
        float4 v = p[(size_t)kz * 73728 + e];
        s.x += v.x; s.y += v.y; s.z += v.z; s.w += v.w;
    }
    ((float4*)out)[e] = s;
}

// ---------------------------------------------------------------------------
extern "C" void kernel_launch(void* const* d_in, const int* in_sizes, int n_in,
                              void* d_out, int out_size, void* d_ws, size_t ws_size,
                              hipStream_t stream) {
    const float* act   = (const float*)d_in[0];
    const float* act2d = (const float*)d_in[1];
    const float* smask = (const float*)d_in[2];
    const float* rot   = (const float*)d_in[3];
    const float* trans = (const float*)d_in[4];
    const float* wq    = (const float*)d_in[5];
    const float* wk    = (const float*)d_in[6];
    const float* wvv   = (const float*)d_in[7];
    const float* wqp   = (const float*)d_in[8];
    const float* bqp   = (const float*)d_in[9];
    const float* wkp   = (const float*)d_in[10];
    const float* bkp   = (const float*)d_in[11];
    const float* wvp   = (const float*)d_in[12];
    const float* bvp   = (const float*)d_in[13];
    const float* w2d   = (const float*)d_in[14];
    // d_in[15] = b2d: constant over k, cancels in softmax over k -> unused
    const float* wfin  = (const float*)d_in[16];
    const float* bfin  = (const float*)d_in[17];
    const float* tw    = (const float*)d_in[18];

    float* W     = (float*)d_ws;
    float* proj  = W;                      // 768*1152
    float* Qv    = proj  + 768 * NPROJ;    // 768*12*28
    float* Kv    = Qv    + 768 * NH * QKD;
    float* akArr = Kv    + 768 * NH * QKD; // 768*12
    float* vvA   = akArr + 768 * NH;       // 768*480
    float* qkBuf = vvA   + 768 * VVD;      // 768*12*768 (7.08M floats)
    float* F     = qkBuf + 768 * NH * NRES;// 768*2112
    float* part  = qkBuf;                  // k5 partials alias qkBuf (dead by then;
                                           // needs 11*768*384 = 3.24M floats < 7.08M)

    k1_proj<<<dim3(18, 12), 256, 0, stream>>>(act, wq, wk, wvv, wqp, wkp, wvp,
                                              bqp, bkp, bvp, proj);
    k2_prep<<<dim3(NRES), 64, 0, stream>>>(proj, rot, trans, tw, Qv, Kv, akArr, vvA);
    k2b_qk<<<dim3(12, 12, NH), 256, 0, stream>>>(Qv, Kv, akArr, qkBuf);
    kA_bias<<<dim3(12, NRES), 256, 0, stream>>>(act2d, smask, w2d, qkBuf);
    kC_attn<<<dim3(NRES), 256, 0, stream>>>(act2d, qkBuf, vvA, rot, trans, F);
    k5_partial<<<dim3(6, 12, KSPLIT), 256, 0, stream>>>(F, wfin, part);
    k5_reduce<<<dim3(288), 256, 0, stream>>>(part, bfin, (float*)d_out);
}

// Round 5
// 686.795 us; speedup vs baseline: 3.9609x; 1.0319x over previous
//
#include <hip/hip_runtime.h>
#include <math.h>

// Problem constants (B=1)
#define NH    12      // heads
#define NRES  768     // sequence length
#define C1V   384
#define C2V   128
#define NPROJ 1152    // 192+192+192+144+144+288
#define QKD   28      // 16 scalar + 12 point dims
#define FDIM  2112    // 192 + 3*96 + 96 + 1536
#define VVD   480     // 192 (v) + 288 (vp global)
#define APAD  772     // attn row pad
#define KSPLIT 11     // k5 split-K factor (2112 = 11 * 192)

typedef __attribute__((ext_vector_type(8))) short bf16x8;
typedef __attribute__((ext_vector_type(4))) float f32x4;

__device__ __forceinline__ float softplusf_(float x) {
    return (x > 20.f) ? x : log1pf(__expf(x));
}
__device__ __forceinline__ ushort f2bf(float x) {   // RNE f32 -> bf16
    union { float f; unsigned u; } v; v.f = x;
    unsigned r = (v.u + 0x7fffu + ((v.u >> 16) & 1u)) >> 16;
    return (ushort)r;
}

// ---------------------------------------------------------------------------
// KW: w2dT[h][c] bf16, h padded to 16 with zeros. w2d is [c=128][h=12] f32.
// ---------------------------------------------------------------------------
__global__ __launch_bounds__(256) void kW_prep(
    const float* __restrict__ w2d, ushort* __restrict__ w2dT)
{
    int idx = blockIdx.x * 256 + threadIdx.x;     // 2048 total
    int h = idx >> 7, c = idx & 127;
    w2dT[idx] = (h < NH) ? f2bf(w2d[c * NH + h]) : (ushort)0;
}

// ---------------------------------------------------------------------------
// K1: proj = act @ [wq|wk|wv|wqp|wkp|wvp] + [0|0|0|bqp|bkp|bvp]
// ---------------------------------------------------------------------------
__global__ __launch_bounds__(256) void k1_proj(
    const float* __restrict__ act,
    const float* __restrict__ wq, const float* __restrict__ wk,
    const float* __restrict__ wv, const float* __restrict__ wqp,
    const float* __restrict__ wkp, const float* __restrict__ wvp,
    const float* __restrict__ bqp, const float* __restrict__ bkp,
    const float* __restrict__ bvp, float* __restrict__ proj)
{
    __shared__ float As[64 * 33];
    __shared__ float Bs[32 * 65];
    const int n0 = blockIdx.x * 64, m0 = blockIdx.y * 64;
    const int tid = threadIdx.x;
    const int tx = tid & 15, ty = tid >> 4;
    float c[4][4] = {};

    for (int kt = 0; kt < C1V; kt += 32) {
        for (int idx = tid; idx < 64 * 32; idx += 256) {
            int r = idx >> 5, j = idx & 31;
            As[r * 33 + j] = act[(m0 + r) * C1V + kt + j];
        }
        for (int idx = tid; idx < 32 * 64; idx += 256) {
            int r = idx >> 6, col = idx & 63;
            int jj = n0 + col, k = kt + r;
            float w;
            if      (jj < 192) w = wq [k * 192 + jj];
            else if (jj < 384) w = wk [k * 192 + jj - 192];
            else if (jj < 576) w = wv [k * 192 + jj - 384];
            else if (jj < 720) w = wqp[k * 144 + jj - 576];
            else if (jj < 864) w = wkp[k * 144 + jj - 720];
            else               w = wvp[k * 288 + jj - 864];
            Bs[r * 65 + col] = w;
        }
        __syncthreads();
        #pragma unroll
        for (int kk = 0; kk < 32; ++kk) {
            float a[4], b[4];
            #pragma unroll
            for (int i = 0; i < 4; ++i) a[i] = As[(ty * 4 + i) * 33 + kk];
            #pragma unroll
            for (int j = 0; j < 4; ++j) b[j] = Bs[kk * 65 + tx * 4 + j];
            #pragma unroll
            for (int i = 0; i < 4; ++i)
                #pragma unroll
                for (int j = 0; j < 4; ++j) c[i][j] += a[i] * b[j];
        }
        __syncthreads();
    }
    float biasv[4];
    #pragma unroll
    for (int j = 0; j < 4; ++j) {
        int col = n0 + tx * 4 + j;
        biasv[j] = (col >= 864) ? bvp[col - 864]
                 : (col >= 720) ? bkp[col - 720]
                 : (col >= 576) ? bqp[col - 576] : 0.f;
    }
    #pragma unroll
    for (int i = 0; i < 4; ++i) {
        float4 v;
        v.x = c[i][0] + biasv[0]; v.y = c[i][1] + biasv[1];
        v.z = c[i][2] + biasv[2]; v.w = c[i][3] + biasv[3];
        *(float4*)&proj[(m0 + ty * 4 + i) * NPROJ + n0 + tx * 4] = v;
    }
}

// ---------------------------------------------------------------------------
// K2: per-residue prep. Qv[n][h][28], Kv[n][h][28], ak[n][h], vv[n][480].
// ---------------------------------------------------------------------------
__global__ __launch_bounds__(64) void k2_prep(
    const float* __restrict__ proj, const float* __restrict__ rot,
    const float* __restrict__ trans, const float* __restrict__ tw,
    float* __restrict__ Qv, float* __restrict__ Kv,
    float* __restrict__ akArr, float* __restrict__ vv)
{
    const int n = blockIdx.x, tid = threadIdx.x;
    __shared__ float kp2[48];
    const float* pr = proj + n * NPROJ;
    float R[9], T[3];
    #pragma unroll
    for (int i = 0; i < 9; ++i) R[i] = rot[n * 9 + i];
    #pragma unroll
    for (int i = 0; i < 3; ++i) T[i] = trans[n * 3 + i];

    for (int idx = tid; idx < 192; idx += 64) {
        int h = idx >> 4, cc = idx & 15;
        Qv[(n * NH + h) * QKD + cc] = pr[idx] * 0.25f;          // sqrt(1/16)
        Kv[(n * NH + h) * QKD + cc] = pr[192 + idx];
        vv[n * VVD + idx] = pr[384 + idx];                      // v
    }
    if (tid < 48) {
        int h = tid >> 2, p = tid & 3;
        float pwh = 0.23570226039551584f * softplusf_(tw[h]);   // sqrt(2/36)*softplus
        float lx = pr[576 + h * 12 + p];
        float ly = pr[576 + h * 12 + 4 + p];
        float lz = pr[576 + h * 12 + 8 + p];
        float gx = R[0] * lx + R[1] * ly + R[2] * lz + T[0];
        float gy = R[3] * lx + R[4] * ly + R[5] * lz + T[1];
        float gz = R[6] * lx + R[7] * ly + R[8] * lz + T[2];
        float* qd = &Qv[(n * NH + h) * QKD + 16];
        qd[p] = pwh * gx; qd[4 + p] = pwh * gy; qd[8 + p] = pwh * gz;
        lx = pr[720 + h * 12 + p];
        ly = pr[720 + h * 12 + 4 + p];
        lz = pr[720 + h * 12 + 8 + p];
        gx = R[0] * lx + R[1] * ly + R[2] * lz + T[0];
        gy = R[3] * lx + R[4] * ly + R[5] * lz + T[1];
        gz = R[6] * lx + R[7] * ly + R[8] * lz + T[2];
        float* kd = &Kv[(n * NH + h) * QKD + 16];
        kd[p] = gx; kd[4 + p] = gy; kd[8 + p] = gz;
        kp2[tid] = gx * gx + gy * gy + gz * gz;
    }
    __syncthreads();
    if (tid < NH) {
        float pwh = 0.23570226039551584f * softplusf_(tw[tid]);
        akArr[n * NH + tid] = -0.5f * pwh *
            (kp2[tid * 4] + kp2[tid * 4 + 1] + kp2[tid * 4 + 2] + kp2[tid * 4 + 3]);
    }
    for (int idx = tid; idx < 96; idx += 64) {
        int h = idx >> 3, p = idx & 7;
        float lx = pr[864 + h * 24 + p];
        float ly = pr[864 + h * 24 + 8 + p];
        float lz = pr[864 + h * 24 + 16 + p];
        float gx = R[0] * lx + R[1] * ly + R[2] * lz + T[0];
        float gy = R[3] * lx + R[4] * ly + R[5] * lz + T[1];
        float gz = R[6] * lx + R[7] * ly + R[8] * lz + T[2];
        float* dst = &vv[n * VVD + 192 + h * 24 + p * 3];
        dst[0] = gx; dst[1] = gy; dst[2] = gz;
    }
}

// ---------------------------------------------------------------------------
// K2b: qkBuf[q][h][k] = Qv[q,h,:].Kv[k,h,:] + ak[k,h]
// ---------------------------------------------------------------------------
__global__ __launch_bounds__(256) void k2b_qk(
    const float* __restrict__ Qv, const float* __restrict__ Kv,
    const float* __restrict__ akArr, float* __restrict__ qkBuf)
{
    const int h = blockIdx.z;
    const int k0 = blockIdx.x * 64, q0 = blockIdx.y * 64;
    __shared__ float As[64 * 29];
    __shared__ float Bs[64 * 29];
    const int tid = threadIdx.x, tx = tid & 15, ty = tid >> 4;

    for (int idx = tid; idx < 64 * 28; idx += 256) {
        int r = idx / 28, j = idx - r * 28;
        As[r * 29 + j] = Qv[((q0 + r) * NH + h) * QKD + j];
        Bs[r * 29 + j] = Kv[((k0 + r) * NH + h) * QKD + j];
    }
    __syncthreads();
    float c[4][4] = {};
    #pragma unroll
    for (int kk = 0; kk < 28; ++kk) {
        float a[4], b[4];
        #pragma unroll
        for (int i = 0; i < 4; ++i) a[i] = As[(ty * 4 + i) * 29 + kk];
        #pragma unroll
        for (int j = 0; j < 4; ++j) b[j] = Bs[(tx * 4 + j) * 29 + kk];
        #pragma unroll
        for (int i = 0; i < 4; ++i)
            #pragma unroll
            for (int j = 0; j < 4; ++j) c[i][j] += a[i] * b[j];
    }
    float akv[4];
    #pragma unroll
    for (int j = 0; j < 4; ++j) akv[j] = akArr[(k0 + tx * 4 + j) * NH + h];
    #pragma unroll
    for (int i = 0; i < 4; ++i) {
        float4 v;
        v.x = c[i][0] + akv[0]; v.y = c[i][1] + akv[1];
        v.z = c[i][2] + akv[2]; v.w = c[i][3] + akv[3];
        *(float4*)&qkBuf[((q0 + ty * 4 + i) * NH + h) * NRES + k0 + tx * 4] = v;
    }
}

// ---------------------------------------------------------------------------
// KA: logits += act2d @ w2d via bf16 MFMA.  grid (12 ktiles, 768 q).
//   Stage 64x128 act2d tile as bf16 (converted in-register, LDS stride 136).
//   Each wave: one 16(k-rows)x16(h) D-tile, K=128 -> 4 MFMAs.
//   Epilogue: per-lane RMW of qkBuf[q][h][k] with mask + sqrt(1/3).
// ---------------------------------------------------------------------------
__global__ __launch_bounds__(256) void kA_mfma(
    const float* __restrict__ act2d, const float* __restrict__ smask,
    const ushort* __restrict__ w2dT, float* __restrict__ qkBuf)
{
    const int q = blockIdx.y, k0 = blockIdx.x * 64, tid = threadIdx.x;
    __shared__ ushort tile[64 * 136];    // 17.4 KB
    const int lane = tid & 63, wv = tid >> 6;
    const int nb = lane & 15, quad = lane >> 4;

    // B-frags (w2d), same for all waves: B[k=quad*8+j+32s][n=nb]
    bf16x8 bfr[4];
    #pragma unroll
    for (int s = 0; s < 4; ++s)
        bfr[s] = *(const bf16x8*)&w2dT[nb * 128 + quad * 8 + s * 32];

    // stage + convert
    const float* src = act2d + ((size_t)q * NRES + k0) * C2V;
    #pragma unroll
    for (int i = 0; i < 8; ++i) {
        int f = tid + i * 256;               // 2048 float4-chunks (64 rows x 32)
        int r = f >> 5, c4 = f & 31;
        float4 v = ((const float4*)src)[f];
        ushort4 o = { f2bf(v.x), f2bf(v.y), f2bf(v.z), f2bf(v.w) };
        *(ushort4*)&tile[r * 136 + c4 * 4] = o;
    }
    __syncthreads();

    f32x4 acc = {0.f, 0.f, 0.f, 0.f};
    #pragma unroll
    for (int s = 0; s < 4; ++s) {
        bf16x8 af = *(const bf16x8*)&tile[(wv * 16 + nb) * 136 + quad * 8 + s * 32];
        acc = __builtin_amdgcn_mfma_f32_16x16x32_bf16(af, bfr[s], acc, 0, 0, 0);
    }

    // epilogue: col = nb = h; rows = k0 + wv*16 + quad*4 + reg
    if (nb < NH) {
        const int kb = k0 + wv * 16 + quad * 4;
        float* dst = &qkBuf[((size_t)(q * NH + nb)) * NRES + kb];
        float4 old = *(float4*)dst;
        float4 sm = *(const float4*)&smask[kb];
        const float smq = smask[q];
        const float scale = 0.5773502691896258f;   // sqrt(1/3)
        float4 outv;
        outv.x = (old.x + acc[0] - 1e5f * (1.f - smq * sm.x)) * scale;
        outv.y = (old.y + acc[1] - 1e5f * (1.f - smq * sm.y)) * scale;
        outv.z = (old.z + acc[2] - 1e5f * (1.f - smq * sm.z)) * scale;
        outv.w = (old.w + acc[3] - 1e5f * (1.f - smq * sm.w)) * scale;
        *(float4*)dst = outv;
    }
}

// ---------------------------------------------------------------------------
// KC: per-q softmax + r2d (direct coalesced global act2d reads, no tile)
//     + vv pass.  LDS ~43.5 KB -> 3 blocks/CU.
// ---------------------------------------------------------------------------
__global__ __launch_bounds__(256) void kC_attn(
    const float* __restrict__ act2d, const float* __restrict__ qkBuf,
    const float* __restrict__ vv, const float* __restrict__ rot,
    const float* __restrict__ trans, float* __restrict__ F)
{
    const int q = blockIdx.x, tid = threadIdx.x;
    __shared__ float attnS[NH * APAD];     // 37.1 KB, unnormalized exp
    __shared__ float scr[1536];            // 6 KB scratch
    __shared__ float red[NH * 4];
    __shared__ float mh[NH], lh[NH];
    __shared__ float rotS[9], transS[3];

    if (tid < 9) rotS[tid] = rot[q * 9 + tid];
    if (tid < 3) transS[tid] = trans[q * 3 + tid];

    // ---- logits (masked+scaled by kA) ----
    float lg[3][NH];
    #pragma unroll
    for (int h = 0; h < NH; ++h)
        #pragma unroll
        for (int i = 0; i < 3; ++i)
            lg[i][h] = qkBuf[((size_t)(q * NH + h)) * NRES + tid + 256 * i];

    // ---- softmax over k ----
    const int wv_ = tid >> 6, lane = tid & 63;
    #pragma unroll
    for (int h = 0; h < NH; ++h) {
        float v = fmaxf(fmaxf(lg[0][h], lg[1][h]), lg[2][h]);
        for (int off = 32; off > 0; off >>= 1) v = fmaxf(v, __shfl_down(v, off, 64));
        if (lane == 0) red[h * 4 + wv_] = v;
    }
    __syncthreads();
    if (tid < NH)
        mh[tid] = fmaxf(fmaxf(red[tid * 4], red[tid * 4 + 1]),
                        fmaxf(red[tid * 4 + 2], red[tid * 4 + 3]));
    __syncthreads();
    float lsum[NH];
    #pragma unroll
    for (int h = 0; h < NH; ++h) lsum[h] = 0.f;
    #pragma unroll
    for (int i = 0; i < 3; ++i)
        #pragma unroll
        for (int h = 0; h < NH; ++h) {
            float e = __expf(lg[i][h] - mh[h]);
            attnS[h * APAD + tid + 256 * i] = e;
            lsum[h] += e;
        }
    #pragma unroll
    for (int h = 0; h < NH; ++h) {
        float v = lsum[h];
        for (int off = 32; off > 0; off >>= 1) v += __shfl_down(v, off, 64);
        if (lane == 0) red[h * 4 + wv_] = v;
    }
    __syncthreads();
    if (tid < NH)
        lh[tid] = 1.f / (red[tid * 4] + red[tid * 4 + 1] + red[tid * 4 + 2] + red[tid * 4 + 3]);
    __syncthreads();

    // ---- r2d: direct global streaming ----
    // thread = (cq 0..31, hg 0..3, kg 0..1): c = 4cq.., h = 3hg.., k-half kg
    const int cq = tid & 31, hg = (tid >> 5) & 3, kg = tid >> 7;
    const int h0 = 3 * hg;
    const float* abase = act2d + ((size_t)q * NRES + kg * 384) * C2V + cq * 4;
    const float* at0 = &attnS[(h0    ) * APAD + kg * 384];
    const float* at1 = &attnS[(h0 + 1) * APAD + kg * 384];
    const float* at2 = &attnS[(h0 + 2) * APAD + kg * 384];
    float4 a0 = {0,0,0,0}, a1 = {0,0,0,0}, a2 = {0,0,0,0};

    for (int kk = 0; kk < 384; kk += 4) {
        float4 t0 = *(const float4*)&abase[(size_t)(kk    ) * C2V];
        float4 t1 = *(const float4*)&abase[(size_t)(kk + 1) * C2V];
        float4 t2 = *(const float4*)&abase[(size_t)(kk + 2) * C2V];
        float4 t3 = *(const float4*)&abase[(size_t)(kk + 3) * C2V];
        float4 p0 = *(const float4*)&at0[kk];
        float4 p1 = *(const float4*)&at1[kk];
        float4 p2 = *(const float4*)&at2[kk];
        a0.x += p0.x*t0.x + p0.y*t1.x + p0.z*t2.x + p0.w*t3.x;
        a0.y += p0.x*t0.y + p0.y*t1.y + p0.z*t2.y + p0.w*t3.y;
        a0.z += p0.x*t0.z + p0.y*t1.z + p0.z*t2.z + p0.w*t3.z;
        a0.w += p0.x*t0.w + p0.y*t1.w + p0.z*t2.w + p0.w*t3.w;
        a1.x += p1.x*t0.x + p1.y*t1.x + p1.z*t2.x + p1.w*t3.x;
        a1.y += p1.x*t0.y + p1.y*t1.y + p1.z*t2.y + p1.w*t3.y;
        a1.z += p1.x*t0.z + p1.y*t1.z + p1.z*t2.z + p1.w*t3.z;
        a1.w += p1.x*t0.w + p1.y*t1.w + p1.z*t2.w + p1.w*t3.w;
        a2.x += p2.x*t0.x + p2.y*t1.x + p2.z*t2.x + p2.w*t3.x;
        a2.y += p2.x*t0.y + p2.y*t1.y + p2.z*t2.y + p2.w*t3.y;
        a2.z += p2.x*t0.z + p2.y*t1.z + p2.z*t2.z + p2.w*t3.z;
        a2.w += p2.x*t0.w + p2.y*t1.w + p2.z*t2.w + p2.w*t3.w;
    }
    if (kg == 1) {
        *(float4*)&scr[(h0    ) * 128 + cq * 4] = a0;
        *(float4*)&scr[(h0 + 1) * 128 + cq * 4] = a1;
        *(float4*)&scr[(h0 + 2) * 128 + cq * 4] = a2;
    }
    __syncthreads();
    float* Fq = F + q * FDIM;
    if (kg == 0) {
        float4 b0 = *(const float4*)&scr[(h0    ) * 128 + cq * 4];
        float4 b1 = *(const float4*)&scr[(h0 + 1) * 128 + cq * 4];
        float4 b2 = *(const float4*)&scr[(h0 + 2) * 128 + cq * 4];
        float l0 = lh[h0], l1 = lh[h0 + 1], l2 = lh[h0 + 2];
        float4 o0 = {(a0.x+b0.x)*l0, (a0.y+b0.y)*l0, (a0.z+b0.z)*l0, (a0.w+b0.w)*l0};
        float4 o1 = {(a1.x+b1.x)*l1, (a1.y+b1.y)*l1, (a1.z+b1.z)*l1, (a1.w+b1.w)*l1};
        float4 o2 = {(a2.x+b2.x)*l2, (a2.y+b2.y)*l2, (a2.z+b2.z)*l2, (a2.w+b2.w)*l2};
        *(float4*)&Fq[576 + (h0    ) * 128 + cq * 4] = o0;
        *(float4*)&Fq[576 + (h0 + 1) * 128 + cq * 4] = o1;
        *(float4*)&Fq[576 + (h0 + 2) * 128 + cq * 4] = o2;
    }
    __syncthreads();

    // ---- vv pass: out[j] = sum_k attn[hmap(j)][k] * vv[k][j], j in [0,480) ----
    const int j4 = tid & 127;                    // active if j4 < 120
    const int kgv = tid >> 7;
    float p0 = 0.f, p1 = 0.f, p2 = 0.f, p3 = 0.f;
    if (j4 < 120) {
        const int h = (j4 < 48) ? (j4 >> 2) : ((j4 - 48) / 6);
        const float* at = &attnS[h * APAD + kgv * 384];
        const float* col = vv + (size_t)(kgv * 384) * VVD + j4 * 4;
        #pragma unroll 4
        for (int k = 0; k < 384; ++k) {
            float a = at[k];
            float4 v = *(const float4*)(col + (size_t)k * VVD);
            p0 += a * v.x; p1 += a * v.y; p2 += a * v.z; p3 += a * v.w;
        }
    }
    __syncthreads();
    if (j4 < 120) {
        float4 pv = {p0, p1, p2, p3};
        *(float4*)&scr[(kgv * 120 + j4) * 4] = pv;
    }
    __syncthreads();
    if (tid < 120) {
        float4 a = *(const float4*)&scr[tid * 4];
        float4 b = *(const float4*)&scr[(120 + tid) * 4];
        const int h = (tid < 48) ? (tid >> 2) : ((tid - 48) / 6);
        const float il = lh[h];
        float4 s = {(a.x + b.x) * il, (a.y + b.y) * il,
                    (a.z + b.z) * il, (a.w + b.w) * il};
        if (tid < 48) {
            *(float4*)&Fq[tid * 4] = s;                 // res_scalar (192)
        } else {
            *(float4*)&scr[1024 + (tid - 48) * 4] = s;  // rpg (288)
        }
    }
    __syncthreads();
    if (tid < 96) {
        float gx = scr[1024 + tid * 3]     - transS[0];
        float gy = scr[1024 + tid * 3 + 1] - transS[1];
        float gz = scr[1024 + tid * 3 + 2] - transS[2];
        // invert_apply: rpl_i = sum_j R[j][i] * g_j
        float x = rotS[0] * gx + rotS[3] * gy + rotS[6] * gz;
        float y = rotS[1] * gx + rotS[4] * gy + rotS[7] * gz;
        float z = rotS[2] * gx + rotS[5] * gy + rotS[8] * gz;
        Fq[192 + tid] = x;
        Fq[288 + tid] = y;
        Fq[384 + tid] = z;
        Fq[480 + tid] = sqrtf(x * x + y * y + z * z);
    }
}

// ---------------------------------------------------------------------------
// K5: split-K partials + reduce.
// ---------------------------------------------------------------------------
__global__ __launch_bounds__(256) void k5_partial(
    const float* __restrict__ F, const float* __restrict__ wfin,
    float* __restrict__ part)
{
    const int n0 = blockIdx.x * 64, m0 = blockIdx.y * 64, kz = blockIdx.z;
    const int kbeg = kz * 192;
    __shared__ float As[64 * 33];
    __shared__ float Bs[32 * 65];
    const int tid = threadIdx.x, tx = tid & 15, ty = tid >> 4;
    float c[4][4] = {};

    for (int kt = kbeg; kt < kbeg + 192; kt += 32) {
        for (int idx = tid; idx < 64 * 32; idx += 256) {
            int r = idx >> 5, j = idx & 31;
            As[r * 33 + j] = F[(m0 + r) * FDIM + kt + j];
        }
        for (int idx = tid; idx < 32 * 64; idx += 256) {
            int r = idx >> 6, col = idx & 63;
            Bs[r * 65 + col] = wfin[(kt + r) * 384 + n0 + col];
        }
        __syncthreads();
        #pragma unroll
        for (int kk = 0; kk < 32; ++kk) {
            float a[4], b[4];
            #pragma unroll
            for (int i = 0; i < 4; ++i) a[i] = As[(ty * 4 + i) * 33 + kk];
            #pragma unroll
            for (int j = 0; j < 4; ++j) b[j] = Bs[kk * 65 + tx * 4 + j];
            #pragma unroll
            for (int i = 0; i < 4; ++i)
                #pragma unroll
                for (int j = 0; j < 4; ++j) c[i][j] += a[i] * b[j];
        }
        __syncthreads();
    }
    float* dst = part + (size_t)kz * (768 * 384);
    #pragma unroll
    for (int i = 0; i < 4; ++i) {
        float4 v = {c[i][0], c[i][1], c[i][2], c[i][3]};
        *(float4*)&dst[(m0 + ty * 4 + i) * 384 + n0 + tx * 4] = v;
    }
}

__global__ __launch_bounds__(256) void k5_reduce(
    const float* __restrict__ part, const float* __restrict__ bfin,
    float* __restrict__ out)
{
    const int e = blockIdx.x * 256 + threadIdx.x;      // float4 index, 73728 total
    const float4* p = (const float4*)part;
    float4 b = ((const float4*)bfin)[e % 96];
    float4 s = {b.x, b.y, b.z, b.w};
    #pragma unroll
    for (int kz = 0; kz < KSPLIT; ++kz) {
        float4 v = p[(size_t)kz * 73728 + e];
        s.x += v.x; s.y += v.y; s.z += v.z; s.w += v.w;
    }
    ((float4*)out)[e] = s;
}

// ---------------------------------------------------------------------------
extern "C" void kernel_launch(void* const* d_in, const int* in_sizes, int n_in,
                              void* d_out, int out_size, void* d_ws, size_t ws_size,
                              hipStream_t stream) {
    const float* act   = (const float*)d_in[0];
    const float* act2d = (const float*)d_in[1];
    const float* smask = (const float*)d_in[2];
    const float* rot   = (const float*)d_in[3];
    const float* trans = (const float*)d_in[4];
    const float* wq    = (const float*)d_in[5];
    const float* wk    = (const float*)d_in[6];
    const float* wvv   = (const float*)d_in[7];
    const float* wqp   = (const float*)d_in[8];
    const float* bqp   = (const float*)d_in[9];
    const float* wkp   = (const float*)d_in[10];
    const float* bkp   = (const float*)d_in[11];
    const float* wvp   = (const float*)d_in[12];
    const float* bvp   = (const float*)d_in[13];
    const float* w2d   = (const float*)d_in[14];
    // d_in[15] = b2d: constant over k, cancels in softmax over k -> unused
    const float* wfin  = (const float*)d_in[16];
    const float* bfin  = (const float*)d_in[17];
    const float* tw    = (const float*)d_in[18];

    float* W     = (float*)d_ws;
    float* proj  = W;                      // 768*1152
    float* Qv    = proj  + 768 * NPROJ;    // 768*12*28
    float* Kv    = Qv    + 768 * NH * QKD;
    float* akArr = Kv    + 768 * NH * QKD; // 768*12
    float* vvA   = akArr + 768 * NH;       // 768*480
    float* qkBuf = vvA   + 768 * VVD;      // 768*12*768 (7.08M floats)
    float* F     = qkBuf + 768 * NH * NRES;// 768*2112
    ushort* w2dT = (ushort*)(F + 768 * FDIM); // 2048 bf16
    float* part  = qkBuf;                  // k5 partials alias qkBuf (dead by then)

    kW_prep<<<dim3(8), 256, 0, stream>>>(w2d, w2dT);
    k1_proj<<<dim3(18, 12), 256, 0, stream>>>(act, wq, wk, wvv, wqp, wkp, wvp,
                                              bqp, bkp, bvp, proj);
    k2_prep<<<dim3(NRES), 64, 0, stream>>>(proj, rot, trans, tw, Qv, Kv, akArr, vvA);
    k2b_qk<<<dim3(12, 12, NH), 256, 0, stream>>>(Qv, Kv, akArr, qkBuf);
    kA_mfma<<<dim3(12, NRES), 256, 0, stream>>>(act2d, smask, w2dT, qkBuf);
    kC_attn<<<dim3(NRES), 256, 0, stream>>>(act2d, qkBuf, vvA, rot, trans, F);
    k5_partial<<<dim3(6, 12, KSPLIT), 256, 0, stream>>>(F, wfin, part);
    k5_reduce<<<dim3(288), 256, 0, stream>>>(part, bfin, (float*)d_out);
}